// Round 1
// baseline (1155.007 us; speedup 1.0000x reference)
//
#include <hip/hip_runtime.h>
#include <hip/hip_bf16.h>
#include <cstddef>

#define NNODES 10000
#define NEDGES 160000
#define NH     128
#define NCOMBO 4
#define NMROWS (NCOMBO * NNODES)              // 40000 rows (combo-major)
#define NTILE  48
#define HSTR   132                            // padded h-tile stride (floats)
#define NTILES ((NMROWS + NTILE - 1) / NTILE) // 834

__device__ __forceinline__ float gelu_f(float v) {
    // exact erf gelu (matches jax approximate=False)
    return 0.5f * v * (1.0f + erff(v * 0.70710678118654475f));
}

// -------------------------------------------------------------------------
// Message passing: per edge e, emb = edge_attr[e] @ bondW + bondb (recomputed
// from LDS-staged bondW), then for each combo c:
//   agg[c,dst] += gelu(x[c,src] + emb) * nm[c,src]*nm[c,dst]
// 256 threads = 2 edges x 128 channels.
// -------------------------------------------------------------------------
__global__ __launch_bounds__(256) void msg_kernel(
    const float* __restrict__ xcur,   // [4][N][128]
    const float* __restrict__ nm,     // [4][N]
    const float* __restrict__ ea,     // [E][16]
    const float* __restrict__ bW,     // [16][128]
    const float* __restrict__ bb,     // [128]
    const int*   __restrict__ ei,     // [2][E]
    float* __restrict__ agg)          // [4][N][128]
{
    __shared__ float sW[16 * 128];
    __shared__ float sb[128];
    const int tid = threadIdx.x;
    for (int i = tid; i < 16 * 128; i += 256) sW[i] = bW[i];
    if (tid < 128) sb[tid] = bb[tid];
    __syncthreads();

    const int h   = tid & 127;
    const int sub = tid >> 7;   // 0 or 1 (wave-pair granularity, no intra-wave divergence)

    for (int e = blockIdx.x * 2 + sub; e < NEDGES; e += gridDim.x * 2) {
        const int src = ei[e];
        const int dst = ei[NEDGES + e];
        const float4* eap = reinterpret_cast<const float4*>(ea + (size_t)e * 16);
        const float4 a0 = eap[0], a1 = eap[1], a2 = eap[2], a3 = eap[3];

        float emb = sb[h];
        emb += a0.x * sW[0 * 128 + h]  + a0.y * sW[1 * 128 + h]
             + a0.z * sW[2 * 128 + h]  + a0.w * sW[3 * 128 + h];
        emb += a1.x * sW[4 * 128 + h]  + a1.y * sW[5 * 128 + h]
             + a1.z * sW[6 * 128 + h]  + a1.w * sW[7 * 128 + h];
        emb += a2.x * sW[8 * 128 + h]  + a2.y * sW[9 * 128 + h]
             + a2.z * sW[10 * 128 + h] + a2.w * sW[11 * 128 + h];
        emb += a3.x * sW[12 * 128 + h] + a3.y * sW[13 * 128 + h]
             + a3.z * sW[14 * 128 + h] + a3.w * sW[15 * 128 + h];

        #pragma unroll
        for (int c = 0; c < NCOMBO; ++c) {
            const float em = nm[c * NNODES + src] * nm[c * NNODES + dst];
            const float v  = xcur[((size_t)c * NNODES + src) * NH + h] + emb;
            atomicAdd(&agg[((size_t)c * NNODES + dst) * NH + h], gelu_f(v) * em);
        }
    }
}

// -------------------------------------------------------------------------
// Fused tiled GEMM over [40000,128] rows.
// MODE 0: h = (1+eps)*x + agg ; t = gelu(h@W1 + b1)          -> outp (tbuf)
// MODE 1: u = t@W2 + b2       ; xcur += gelu(u)              -> outp (xcur, RMW)
// MODE 2: t = relu(x@mlpW1 + b1)                             -> outp (tbuf)
// MODE 3: y = t@mlpW2 + b2    ; out_acc[c] += y * nm[row]    -> outp (out_acc, atomics)
// -------------------------------------------------------------------------
template <int MODE>
__global__ __launch_bounds__(256) void gemm_kernel(
    const float* __restrict__ A,      // x (0,2) or tbuf (1,3)
    const float* __restrict__ Bagg,   // agg (mode 0 only)
    const float* __restrict__ W,      // [128][OUTW]
    const float* __restrict__ bias,   // [OUTW]
    const float* __restrict__ epsp,   // eps array (mode 0 only)
    int layer,
    const float* __restrict__ nm,     // [40000] flat mask (mode 3 only)
    float* __restrict__ outp)
{
    constexpr int OUTW = (MODE == 3) ? 64 : 128;
    constexpr int KT   = (MODE == 3) ? 128 : 64;   // K-slice staged in LDS
    constexpr int NKB  = 128 / KT;
    constexpr int CG   = OUTW / 4;                 // channel groups (float4)
    constexpr int NS   = 256 / CG;                 // row slots
    constexpr int RPS  = NTILE / NS;               // rows per slot

    __shared__ float sh[NTILE * HSTR];   // 25,344 B
    __shared__ float sW[128 * 64];       // 32,768 B  (KT*OUTW == 8192 both modes)
    __shared__ float sacc[256];          // mode 3 partial output

    const int tid = threadIdx.x;
    const int cg  = tid % CG;
    const int ns  = tid / CG;

    float epv = 1.0f;
    if constexpr (MODE == 0) epv = 1.0f + epsp[layer];
    if constexpr (MODE == 3) sacc[tid] = 0.0f;   // before first barrier

    for (int tile = blockIdx.x; tile < NTILES; tile += gridDim.x) {
        const int row0 = tile * NTILE;
        __syncthreads();   // protect sh/sW from previous tile's readers

        // ---- stage h tile: NTILE rows x 128 (float4 granularity) ----
        for (int i = tid; i < NTILE * 32; i += 256) {
            const int r  = i >> 5;
            const int kq = i & 31;
            const int gr = row0 + r;
            float4 v = make_float4(0.f, 0.f, 0.f, 0.f);
            if (gr < NMROWS) {
                v = reinterpret_cast<const float4*>(A + (size_t)gr * NH)[kq];
                if constexpr (MODE == 0) {
                    const float4 g = reinterpret_cast<const float4*>(Bagg + (size_t)gr * NH)[kq];
                    v.x = epv * v.x + g.x; v.y = epv * v.y + g.y;
                    v.z = epv * v.z + g.z; v.w = epv * v.w + g.w;
                }
            }
            *reinterpret_cast<float4*>(&sh[r * HSTR + kq * 4]) = v;
        }

        float acc[RPS][4];
        #pragma unroll
        for (int t = 0; t < RPS; ++t) {
            acc[t][0] = 0.f; acc[t][1] = 0.f; acc[t][2] = 0.f; acc[t][3] = 0.f;
        }

        for (int kb = 0; kb < NKB; ++kb) {
            __syncthreads();   // previous sW readers done (also covers sh staging)
            const float* Wk = W + kb * KT * OUTW;
            for (int i = tid * 4; i < KT * OUTW; i += 1024)
                *reinterpret_cast<float4*>(&sW[i]) = *reinterpret_cast<const float4*>(Wk + i);
            __syncthreads();

            for (int k = 0; k < KT; ++k) {
                const float4 w = *reinterpret_cast<const float4*>(&sW[k * OUTW + cg * 4]);
                #pragma unroll
                for (int t = 0; t < RPS; ++t) {
                    const float hv = sh[(ns * RPS + t) * HSTR + kb * KT + k];
                    acc[t][0] += hv * w.x; acc[t][1] += hv * w.y;
                    acc[t][2] += hv * w.z; acc[t][3] += hv * w.w;
                }
            }
        }

        // ---- epilogue ----
        const int ch = cg * 4;
        #pragma unroll
        for (int t = 0; t < RPS; ++t) {
            const int gr = row0 + ns * RPS + t;
            if (gr >= NMROWS) continue;
            float v0 = acc[t][0] + bias[ch + 0];
            float v1 = acc[t][1] + bias[ch + 1];
            float v2 = acc[t][2] + bias[ch + 2];
            float v3 = acc[t][3] + bias[ch + 3];
            if constexpr (MODE == 0) {
                float4 o = make_float4(gelu_f(v0), gelu_f(v1), gelu_f(v2), gelu_f(v3));
                *reinterpret_cast<float4*>(&outp[(size_t)gr * NH + ch]) = o;
            } else if constexpr (MODE == 1) {
                float4 cur = *reinterpret_cast<const float4*>(&outp[(size_t)gr * NH + ch]);
                cur.x += gelu_f(v0); cur.y += gelu_f(v1);
                cur.z += gelu_f(v2); cur.w += gelu_f(v3);
                *reinterpret_cast<float4*>(&outp[(size_t)gr * NH + ch]) = cur;
            } else if constexpr (MODE == 2) {
                float4 o = make_float4(fmaxf(v0, 0.f), fmaxf(v1, 0.f),
                                       fmaxf(v2, 0.f), fmaxf(v3, 0.f));
                *reinterpret_cast<float4*>(&outp[(size_t)gr * NH + ch]) = o;
            } else {
                const float w = nm[gr];
                const int c = gr / NNODES;
                atomicAdd(&sacc[c * 64 + ch + 0], v0 * w);
                atomicAdd(&sacc[c * 64 + ch + 1], v1 * w);
                atomicAdd(&sacc[c * 64 + ch + 2], v2 * w);
                atomicAdd(&sacc[c * 64 + ch + 3], v3 * w);
            }
        }
    }

    if constexpr (MODE == 3) {
        __syncthreads();
        atomicAdd(&outp[tid], sacc[tid]);   // outp = out_acc[256]
    }
}

// -------------------------------------------------------------------------
// Final: out[c][o] = out_acc[c][o] / sum_n nm[c][n].  One wave per combo.
// -------------------------------------------------------------------------
__global__ __launch_bounds__(256) void final_kernel(
    const float* __restrict__ acc, const float* __restrict__ nm,
    float* __restrict__ outp)
{
    const int tid  = threadIdx.x;
    const int c    = tid >> 6;
    const int lane = tid & 63;
    float s = 0.f;
    for (int n = lane; n < NNODES; n += 64) s += nm[c * NNODES + n];
    #pragma unroll
    for (int off = 32; off > 0; off >>= 1) s += __shfl_down(s, off, 64);
    const float denom = __shfl(s, 0, 64);
    outp[tid] = acc[tid] / denom;
}

extern "C" void kernel_launch(void* const* d_in, const int* in_sizes, int n_in,
                              void* d_out, int out_size, void* d_ws, size_t ws_size,
                              hipStream_t stream) {
    const float* x    = (const float*)d_in[0];
    const float* nm   = (const float*)d_in[1];
    const float* ea   = (const float*)d_in[2];
    const float* bW   = (const float*)d_in[3];
    const float* bb   = (const float*)d_in[4];
    const float* cW1  = (const float*)d_in[5];
    const float* cb1  = (const float*)d_in[6];
    const float* cW2  = (const float*)d_in[7];
    const float* cb2  = (const float*)d_in[8];
    const float* eps  = (const float*)d_in[9];
    const float* mW1  = (const float*)d_in[10];
    const float* mb1  = (const float*)d_in[11];
    const float* mW2  = (const float*)d_in[12];
    const float* mb2  = (const float*)d_in[13];
    const int*   ei   = (const int*)d_in[14];

    float* ws   = (float*)d_ws;
    float* xcur = ws;                      // 5,120,000 floats
    float* agg  = ws + 5120000;            // 5,120,000 floats
    float* tbuf = ws + 10240000;           // 5,120,000 floats
    float* oacc = ws + 15360000;           // 256 floats

    hipMemcpyAsync(xcur, x, (size_t)5120000 * 4, hipMemcpyDeviceToDevice, stream);

    for (int l = 0; l < 3; ++l) {
        hipMemsetAsync(agg, 0, (size_t)5120000 * 4, stream);
        msg_kernel<<<2048, 256, 0, stream>>>(xcur, nm, ea, bW, bb, ei, agg);
        gemm_kernel<0><<<NTILES, 256, 0, stream>>>(xcur, agg, cW1 + l * 16384,
                                                   cb1 + l * 128, eps, l, nullptr, tbuf);
        gemm_kernel<1><<<NTILES, 256, 0, stream>>>(tbuf, nullptr, cW2 + l * 16384,
                                                   cb2 + l * 128, nullptr, 0, nullptr, xcur);
    }

    gemm_kernel<2><<<NTILES, 256, 0, stream>>>(xcur, nullptr, mW1, mb1,
                                               nullptr, 0, nullptr, tbuf);
    hipMemsetAsync(oacc, 0, 256 * 4, stream);
    gemm_kernel<3><<<NTILES, 256, 0, stream>>>(tbuf, nullptr, mW2, mb2,
                                               nullptr, 0, nm, oacc);
    final_kernel<<<1, 256, 0, stream>>>(oacc, nm, (float*)d_out);
}

// Round 2
// 711.310 us; speedup vs baseline: 1.6238x; 1.6238x over previous
//
#include <hip/hip_runtime.h>
#include <hip/hip_bf16.h>
#include <cstddef>

#define NNODES 10000
#define NEDGES 160000
#define NH     128
#define NCOMBO 4
#define NMROWS (NCOMBO * NNODES)              // 40000 rows (combo-major)
#define NTILE  48
#define HSTR   132                            // padded h-tile stride (floats)
#define NTILES ((NMROWS + NTILE - 1) / NTILE) // 834

__device__ __forceinline__ float gelu_f(float v) {
    // exact erf gelu (matches jax approximate=False)
    return 0.5f * v * (1.0f + erff(v * 0.70710678118654475f));
}

// ========================= CSR build (by dst) ============================
__global__ __launch_bounds__(256) void hist_kernel(const int* __restrict__ ei,
                                                   int* __restrict__ deg) {
    const int e = blockIdx.x * 256 + threadIdx.x;
    if (e < NEDGES) atomicAdd(&deg[ei[NEDGES + e]], 1);
}

__global__ __launch_bounds__(1024) void scan_kernel(const int* __restrict__ deg,
                                                    int* __restrict__ off,
                                                    int* __restrict__ cursor) {
    __shared__ int ssum[1024];
    const int tid  = threadIdx.x;
    const int base = tid * 10;                 // 1024*10 >= 10000
    int loc[10];
    int s = 0;
    #pragma unroll
    for (int i = 0; i < 10; ++i) {
        const int idx = base + i;
        loc[i] = s;
        s += (idx < NNODES) ? deg[idx] : 0;
    }
    ssum[tid] = s;
    for (int d = 1; d < 1024; d <<= 1) {
        __syncthreads();
        const int t = (tid >= d) ? ssum[tid - d] : 0;
        __syncthreads();
        ssum[tid] += t;
    }
    __syncthreads();
    const int pref = ssum[tid] - s;            // exclusive prefix of this chunk
    #pragma unroll
    for (int i = 0; i < 10; ++i) {
        const int idx = base + i;
        if (idx < NNODES) { off[idx] = pref + loc[i]; cursor[idx] = pref + loc[i]; }
    }
    if (tid == 0) off[NNODES] = NEDGES;
}

__global__ __launch_bounds__(256) void scatter_kernel(const int* __restrict__ ei,
                                                      int* __restrict__ cursor,
                                                      int* __restrict__ esrc,
                                                      int* __restrict__ eidb) {
    const int e = blockIdx.x * 256 + threadIdx.x;
    if (e < NEDGES) {
        const int src = ei[e];
        const int dst = ei[NEDGES + e];
        const int pos = atomicAdd(&cursor[dst], 1);
        esrc[pos] = src;
        eidb[pos] = e;
    }
}

// =============== message passing: per-dst register accumulation ==========
// hout[c,n,:] = (1+eps_l)*x[c,n,:] + sum_{e: dst(e)=n} gelu(x[c,src]+emb_e)*m
// 256 threads = 2 node-slots x 128 channels. bondW column kept in 16 VGPRs.
__global__ __launch_bounds__(256) void agg_kernel(
    const float* __restrict__ xcur,   // [4][N][128]
    const float* __restrict__ nm,     // [4][N]
    const float* __restrict__ ea,     // [E][16]
    const float* __restrict__ bW,     // [16][128]
    const float* __restrict__ bb,     // [128]
    const int*   __restrict__ off,    // [N+1]
    const int*   __restrict__ esrc,   // [E] CSR src
    const int*   __restrict__ eidb,   // [E] CSR original edge id
    const float* __restrict__ epsp, int layer,
    float* __restrict__ hout)         // [4][N][128]
{
    const int tid = threadIdx.x;
    const int h   = tid & 127;
    const int sub = tid >> 7;

    float wc[16];
    #pragma unroll
    for (int k = 0; k < 16; ++k) wc[k] = bW[k * 128 + h];
    const float bbr = bb[h];
    const float epv = 1.0f + epsp[layer];

    for (int n = blockIdx.x * 2 + sub; n < NNODES; n += gridDim.x * 2) {
        float acc0 = 0.f, acc1 = 0.f, acc2 = 0.f, acc3 = 0.f;
        const int j0 = off[n], j1 = off[n + 1];
        const float d0 = nm[0 * NNODES + n];
        const float d1 = nm[1 * NNODES + n];
        const float d2 = nm[2 * NNODES + n];
        const float d3 = nm[3 * NNODES + n];

        for (int j = j0; j < j1; ++j) {
            const int src = esrc[j];
            const int e   = eidb[j];
            const float4* eap = reinterpret_cast<const float4*>(ea + (size_t)e * 16);
            const float4 a0 = eap[0], a1 = eap[1], a2 = eap[2], a3 = eap[3];

            float emb = bbr;
            emb += a0.x * wc[0]  + a0.y * wc[1]  + a0.z * wc[2]  + a0.w * wc[3];
            emb += a1.x * wc[4]  + a1.y * wc[5]  + a1.z * wc[6]  + a1.w * wc[7];
            emb += a2.x * wc[8]  + a2.y * wc[9]  + a2.z * wc[10] + a2.w * wc[11];
            emb += a3.x * wc[12] + a3.y * wc[13] + a3.z * wc[14] + a3.w * wc[15];

            const float m0 = nm[0 * NNODES + src] * d0;
            const float m1 = nm[1 * NNODES + src] * d1;
            const float m2 = nm[2 * NNODES + src] * d2;
            const float m3 = nm[3 * NNODES + src] * d3;
            const float x0 = xcur[((size_t)0 * NNODES + src) * NH + h];
            const float x1 = xcur[((size_t)1 * NNODES + src) * NH + h];
            const float x2 = xcur[((size_t)2 * NNODES + src) * NH + h];
            const float x3 = xcur[((size_t)3 * NNODES + src) * NH + h];

            acc0 += gelu_f(x0 + emb) * m0;
            acc1 += gelu_f(x1 + emb) * m1;
            acc2 += gelu_f(x2 + emb) * m2;
            acc3 += gelu_f(x3 + emb) * m3;
        }

        hout[((size_t)0 * NNODES + n) * NH + h] = epv * xcur[((size_t)0 * NNODES + n) * NH + h] + acc0;
        hout[((size_t)1 * NNODES + n) * NH + h] = epv * xcur[((size_t)1 * NNODES + n) * NH + h] + acc1;
        hout[((size_t)2 * NNODES + n) * NH + h] = epv * xcur[((size_t)2 * NNODES + n) * NH + h] + acc2;
        hout[((size_t)3 * NNODES + n) * NH + h] = epv * xcur[((size_t)3 * NNODES + n) * NH + h] + acc3;
    }
}

// -------------------------------------------------------------------------
// Fused tiled GEMM over [40000,128] rows.
// MODE 0: t = gelu(A@W + b)                     -> outp (store)
// MODE 1: u = A@W + b ; outp += gelu(u)         -> outp (RMW)
// MODE 2: t = relu(A@W + b)                     -> outp (store)
// MODE 3: y = A@W + b ; out_acc[c] += y*nm[row] -> outp (atomics, 256 floats)
// -------------------------------------------------------------------------
template <int MODE>
__global__ __launch_bounds__(256) void gemm_kernel(
    const float* __restrict__ A,
    const float* __restrict__ W,      // [128][OUTW]
    const float* __restrict__ bias,   // [OUTW]
    const float* __restrict__ nm,     // [40000] flat mask (mode 3 only)
    float* __restrict__ outp)
{
    constexpr int OUTW = (MODE == 3) ? 64 : 128;
    constexpr int KT   = (MODE == 3) ? 128 : 64;   // K-slice staged in LDS
    constexpr int NKB  = 128 / KT;
    constexpr int CG   = OUTW / 4;                 // channel groups (float4)
    constexpr int NS   = 256 / CG;                 // row slots
    constexpr int RPS  = NTILE / NS;               // rows per slot

    __shared__ float sh[NTILE * HSTR];   // 25,344 B
    __shared__ float sW[128 * 64];       // 32,768 B  (KT*OUTW == 8192 both modes)
    __shared__ float sacc[256];          // mode 3 partial output

    const int tid = threadIdx.x;
    const int cg  = tid % CG;
    const int ns  = tid / CG;

    if constexpr (MODE == 3) sacc[tid] = 0.0f;   // before first barrier

    for (int tile = blockIdx.x; tile < NTILES; tile += gridDim.x) {
        const int row0 = tile * NTILE;
        __syncthreads();

        for (int i = tid; i < NTILE * 32; i += 256) {
            const int r  = i >> 5;
            const int kq = i & 31;
            const int gr = row0 + r;
            float4 v = make_float4(0.f, 0.f, 0.f, 0.f);
            if (gr < NMROWS)
                v = reinterpret_cast<const float4*>(A + (size_t)gr * NH)[kq];
            *reinterpret_cast<float4*>(&sh[r * HSTR + kq * 4]) = v;
        }

        float acc[RPS][4];
        #pragma unroll
        for (int t = 0; t < RPS; ++t) {
            acc[t][0] = 0.f; acc[t][1] = 0.f; acc[t][2] = 0.f; acc[t][3] = 0.f;
        }

        for (int kb = 0; kb < NKB; ++kb) {
            __syncthreads();
            const float* Wk = W + kb * KT * OUTW;
            for (int i = tid * 4; i < KT * OUTW; i += 1024)
                *reinterpret_cast<float4*>(&sW[i]) = *reinterpret_cast<const float4*>(Wk + i);
            __syncthreads();

            for (int k = 0; k < KT; ++k) {
                const float4 w = *reinterpret_cast<const float4*>(&sW[k * OUTW + cg * 4]);
                #pragma unroll
                for (int t = 0; t < RPS; ++t) {
                    const float hv = sh[(ns * RPS + t) * HSTR + kb * KT + k];
                    acc[t][0] += hv * w.x; acc[t][1] += hv * w.y;
                    acc[t][2] += hv * w.z; acc[t][3] += hv * w.w;
                }
            }
        }

        const int ch = cg * 4;
        #pragma unroll
        for (int t = 0; t < RPS; ++t) {
            const int gr = row0 + ns * RPS + t;
            if (gr >= NMROWS) continue;
            float v0 = acc[t][0] + bias[ch + 0];
            float v1 = acc[t][1] + bias[ch + 1];
            float v2 = acc[t][2] + bias[ch + 2];
            float v3 = acc[t][3] + bias[ch + 3];
            if constexpr (MODE == 0) {
                float4 o = make_float4(gelu_f(v0), gelu_f(v1), gelu_f(v2), gelu_f(v3));
                *reinterpret_cast<float4*>(&outp[(size_t)gr * NH + ch]) = o;
            } else if constexpr (MODE == 1) {
                float4 cur = *reinterpret_cast<const float4*>(&outp[(size_t)gr * NH + ch]);
                cur.x += gelu_f(v0); cur.y += gelu_f(v1);
                cur.z += gelu_f(v2); cur.w += gelu_f(v3);
                *reinterpret_cast<float4*>(&outp[(size_t)gr * NH + ch]) = cur;
            } else if constexpr (MODE == 2) {
                float4 o = make_float4(fmaxf(v0, 0.f), fmaxf(v1, 0.f),
                                       fmaxf(v2, 0.f), fmaxf(v3, 0.f));
                *reinterpret_cast<float4*>(&outp[(size_t)gr * NH + ch]) = o;
            } else {
                const float w = nm[gr];
                const int c = gr / NNODES;
                atomicAdd(&sacc[c * 64 + ch + 0], v0 * w);
                atomicAdd(&sacc[c * 64 + ch + 1], v1 * w);
                atomicAdd(&sacc[c * 64 + ch + 2], v2 * w);
                atomicAdd(&sacc[c * 64 + ch + 3], v3 * w);
            }
        }
    }

    if constexpr (MODE == 3) {
        __syncthreads();
        atomicAdd(&outp[tid], sacc[tid]);   // outp = out_acc[256]
    }
}

// -------------------------------------------------------------------------
__global__ __launch_bounds__(256) void final_kernel(
    const float* __restrict__ acc, const float* __restrict__ nm,
    float* __restrict__ outp)
{
    const int tid  = threadIdx.x;
    const int c    = tid >> 6;
    const int lane = tid & 63;
    float s = 0.f;
    for (int n = lane; n < NNODES; n += 64) s += nm[c * NNODES + n];
    #pragma unroll
    for (int off = 32; off > 0; off >>= 1) s += __shfl_down(s, off, 64);
    const float denom = __shfl(s, 0, 64);
    outp[tid] = acc[tid] / denom;
}

extern "C" void kernel_launch(void* const* d_in, const int* in_sizes, int n_in,
                              void* d_out, int out_size, void* d_ws, size_t ws_size,
                              hipStream_t stream) {
    const float* x    = (const float*)d_in[0];
    const float* nm   = (const float*)d_in[1];
    const float* ea   = (const float*)d_in[2];
    const float* bW   = (const float*)d_in[3];
    const float* bb   = (const float*)d_in[4];
    const float* cW1  = (const float*)d_in[5];
    const float* cb1  = (const float*)d_in[6];
    const float* cW2  = (const float*)d_in[7];
    const float* cb2  = (const float*)d_in[8];
    const float* eps  = (const float*)d_in[9];
    const float* mW1  = (const float*)d_in[10];
    const float* mb1  = (const float*)d_in[11];
    const float* mW2  = (const float*)d_in[12];
    const float* mb2  = (const float*)d_in[13];
    const int*   ei   = (const int*)d_in[14];

    float* ws   = (float*)d_ws;
    float* xcur = ws;                      // 5,120,000 floats
    float* hbuf = ws + 5120000;            // 5,120,000 floats (h / t alias)
    float* oacc = ws + 10240000;           // 256 floats
    int*   ib   = (int*)(ws + 10240256);
    int*   off  = ib;                      // 10001
    int*   cur  = ib + 10002;              // 10000
    int*   deg  = ib + 20002;              // 10000
    int*   esrc = ib + 30002;              // 160000
    int*   eidb = ib + 190002;             // 160000

    hipMemcpyAsync(xcur, x, (size_t)5120000 * 4, hipMemcpyDeviceToDevice, stream);
    hipMemsetAsync(deg, 0, 10000 * 4, stream);
    hist_kernel<<<(NEDGES + 255) / 256, 256, 0, stream>>>(ei, deg);
    scan_kernel<<<1, 1024, 0, stream>>>(deg, off, cur);
    scatter_kernel<<<(NEDGES + 255) / 256, 256, 0, stream>>>(ei, cur, esrc, eidb);

    for (int l = 0; l < 3; ++l) {
        agg_kernel<<<2500, 256, 0, stream>>>(xcur, nm, ea, bW, bb, off, esrc, eidb,
                                             eps, l, hbuf);
        gemm_kernel<0><<<NTILES, 256, 0, stream>>>(hbuf, cW1 + l * 16384,
                                                   cb1 + l * 128, nullptr, hbuf);
        gemm_kernel<1><<<NTILES, 256, 0, stream>>>(hbuf, cW2 + l * 16384,
                                                   cb2 + l * 128, nullptr, xcur);
    }

    gemm_kernel<2><<<NTILES, 256, 0, stream>>>(xcur, mW1, mb1, nullptr, hbuf);
    hipMemsetAsync(oacc, 0, 256 * 4, stream);
    gemm_kernel<3><<<NTILES, 256, 0, stream>>>(hbuf, mW2, mb2, nm, oacc);
    final_kernel<<<1, 256, 0, stream>>>(oacc, nm, (float*)d_out);
}

// Round 4
// 620.660 us; speedup vs baseline: 1.8609x; 1.1461x over previous
//
#include <hip/hip_runtime.h>
#include <hip/hip_bf16.h>
#include <cstddef>

#define NNODES 10000
#define NEDGES 160000
#define NH     128
#define NCOMBO 4
#define NMROWS (NCOMBO * NNODES)              // 40000 rows (combo-major)
#define NTILE  48
#define HSTR   132                            // padded h-tile stride (floats)
#define NTILES ((NMROWS + NTILE - 1) / NTILE) // 834

// Branchless erf-gelu via Abramowitz-Stegun 7.1.26 (|erf err| <= 1.5e-7).
// ~15 VALU slots incl. HW rcp + exp2, vs ~45 for OCML erff (dual-path).
__device__ __forceinline__ float gelu_f(float v) {
    const float u  = v * 0.70710678118654752f;
    float au = __builtin_fabsf(u);
    au = fminf(au, 3.9192f);                       // erf(3.92) = 1 - 1e-8
    const float t  = __builtin_amdgcn_rcpf(__builtin_fmaf(0.3275911f, au, 1.0f));
    const float e  = __builtin_amdgcn_exp2f(au * au * -1.4426950408889634f);
    float p = __builtin_fmaf(1.061405429f, t, -1.453152027f);
    p = __builtin_fmaf(p, t, 1.421413741f);
    p = __builtin_fmaf(p, t, -0.284496736f);
    p = __builtin_fmaf(p, t, 0.254829592f);
    const float erf_abs = 1.0f - p * t * e;        // erf(|u|)
    const float erf_s   = __builtin_copysignf(erf_abs, v);
    return 0.5f * v * (1.0f + erf_s);
}

// ========================= CSR build (by dst) ============================
__global__ __launch_bounds__(256) void hist_kernel(const int* __restrict__ ei,
                                                   int* __restrict__ deg) {
    const int e = blockIdx.x * 256 + threadIdx.x;
    if (e < NEDGES) atomicAdd(&deg[ei[NEDGES + e]], 1);
}

__global__ __launch_bounds__(1024) void scan_kernel(const int* __restrict__ deg,
                                                    int* __restrict__ off,
                                                    int* __restrict__ cursor) {
    __shared__ int ssum[1024];
    const int tid  = threadIdx.x;
    const int base = tid * 10;                 // 1024*10 >= 10000
    int loc[10];
    int s = 0;
    #pragma unroll
    for (int i = 0; i < 10; ++i) {
        const int idx = base + i;
        loc[i] = s;
        s += (idx < NNODES) ? deg[idx] : 0;
    }
    ssum[tid] = s;
    for (int d = 1; d < 1024; d <<= 1) {
        __syncthreads();
        const int t = (tid >= d) ? ssum[tid - d] : 0;
        __syncthreads();
        ssum[tid] += t;
    }
    __syncthreads();
    const int pref = ssum[tid] - s;            // exclusive prefix of this chunk
    #pragma unroll
    for (int i = 0; i < 10; ++i) {
        const int idx = base + i;
        if (idx < NNODES) { off[idx] = pref + loc[i]; cursor[idx] = pref + loc[i]; }
    }
    if (tid == 0) off[NNODES] = NEDGES;
}

// Scatter edges into CSR order; also permute edge_attr rows so agg reads
// them sequentially (drops the eidb indirection + random ea gather).
__global__ __launch_bounds__(256) void scatter_kernel(const int* __restrict__ ei,
                                                      const float* __restrict__ ea,
                                                      int* __restrict__ cursor,
                                                      int* __restrict__ esrc,
                                                      float* __restrict__ ea_s) {
    const int e = blockIdx.x * 256 + threadIdx.x;
    if (e < NEDGES) {
        const int src = ei[e];
        const int dst = ei[NEDGES + e];
        const int pos = atomicAdd(&cursor[dst], 1);
        esrc[pos] = src;
        const float4* s = reinterpret_cast<const float4*>(ea + (size_t)e * 16);
        float4*       d = reinterpret_cast<float4*>(ea_s + (size_t)pos * 16);
        d[0] = s[0]; d[1] = s[1]; d[2] = s[2]; d[3] = s[3];
    }
}

// =============== message passing: per-dst register accumulation ==========
// hout[c,n,:] = (1+eps_l)*x[c,n,:] + sum_{e: dst(e)=n} gelu(x[c,src]+emb_e)*m
// 256 threads = 2 node-slots x 128 channels. bondW column kept in 16 VGPRs.
__global__ __launch_bounds__(256) void agg_kernel(
    const float* __restrict__ xcur,   // [4][N][128]
    const float* __restrict__ nm,     // [4][N]
    const float* __restrict__ ea_s,   // [E][16] CSR-ordered
    const float* __restrict__ bW,     // [16][128]
    const float* __restrict__ bb,     // [128]
    const int*   __restrict__ off,    // [N+1]
    const int*   __restrict__ esrc,   // [E] CSR src
    const float* __restrict__ epsp, int layer,
    float* __restrict__ hout)         // [4][N][128]
{
    const int tid = threadIdx.x;
    const int h   = tid & 127;
    const int sub = tid >> 7;

    float wc[16];
    #pragma unroll
    for (int k = 0; k < 16; ++k) wc[k] = bW[k * 128 + h];
    const float bbr = bb[h];
    const float epv = 1.0f + epsp[layer];

    for (int n = blockIdx.x * 2 + sub; n < NNODES; n += gridDim.x * 2) {
        float acc0 = 0.f, acc1 = 0.f, acc2 = 0.f, acc3 = 0.f;
        const int j0 = off[n], j1 = off[n + 1];
        const float d0 = nm[0 * NNODES + n];
        const float d1 = nm[1 * NNODES + n];
        const float d2 = nm[2 * NNODES + n];
        const float d3 = nm[3 * NNODES + n];

        for (int j = j0; j < j1; ++j) {
            const int src = esrc[j];
            const float4* eap = reinterpret_cast<const float4*>(ea_s + (size_t)j * 16);
            const float4 a0 = eap[0], a1 = eap[1], a2 = eap[2], a3 = eap[3];

            float emb = bbr;
            emb += a0.x * wc[0]  + a0.y * wc[1]  + a0.z * wc[2]  + a0.w * wc[3];
            emb += a1.x * wc[4]  + a1.y * wc[5]  + a1.z * wc[6]  + a1.w * wc[7];
            emb += a2.x * wc[8]  + a2.y * wc[9]  + a2.z * wc[10] + a2.w * wc[11];
            emb += a3.x * wc[12] + a3.y * wc[13] + a3.z * wc[14] + a3.w * wc[15];

            const float m0 = nm[0 * NNODES + src] * d0;
            const float m1 = nm[1 * NNODES + src] * d1;
            const float m2 = nm[2 * NNODES + src] * d2;
            const float m3 = nm[3 * NNODES + src] * d3;
            const float x0 = xcur[((size_t)0 * NNODES + src) * NH + h];
            const float x1 = xcur[((size_t)1 * NNODES + src) * NH + h];
            const float x2 = xcur[((size_t)2 * NNODES + src) * NH + h];
            const float x3 = xcur[((size_t)3 * NNODES + src) * NH + h];

            acc0 += gelu_f(x0 + emb) * m0;
            acc1 += gelu_f(x1 + emb) * m1;
            acc2 += gelu_f(x2 + emb) * m2;
            acc3 += gelu_f(x3 + emb) * m3;
        }

        hout[((size_t)0 * NNODES + n) * NH + h] = epv * xcur[((size_t)0 * NNODES + n) * NH + h] + acc0;
        hout[((size_t)1 * NNODES + n) * NH + h] = epv * xcur[((size_t)1 * NNODES + n) * NH + h] + acc1;
        hout[((size_t)2 * NNODES + n) * NH + h] = epv * xcur[((size_t)2 * NNODES + n) * NH + h] + acc2;
        hout[((size_t)3 * NNODES + n) * NH + h] = epv * xcur[((size_t)3 * NNODES + n) * NH + h] + acc3;
    }
}

// -------------------------------------------------------------------------
// Fused tiled GEMM over [40000,128] rows.
// MODE 0: t = gelu(A@W + b)                     -> outp (store)
// MODE 1: u = A@W + b ; outp += gelu(u)         -> outp (RMW)
// MODE 2: t = relu(A@W + b)                     -> outp (store)
// MODE 3: y = A@W + b ; out_acc[c] += y*nm[row] -> outp (atomics, 256 floats)
// -------------------------------------------------------------------------
template <int MODE>
__global__ __launch_bounds__(256) void gemm_kernel(
    const float* __restrict__ A,
    const float* __restrict__ W,      // [128][OUTW]
    const float* __restrict__ bias,   // [OUTW]
    const float* __restrict__ nm,     // [40000] flat mask (mode 3 only)
    float* __restrict__ outp)
{
    constexpr int OUTW = (MODE == 3) ? 64 : 128;
    constexpr int KT   = (MODE == 3) ? 128 : 64;   // K-slice staged in LDS
    constexpr int NKB  = 128 / KT;
    constexpr int CG   = OUTW / 4;                 // channel groups (float4)
    constexpr int NS   = 256 / CG;                 // row slots
    constexpr int RPS  = NTILE / NS;               // rows per slot

    __shared__ float sh[NTILE * HSTR];   // 25,344 B
    __shared__ float sW[128 * 64];       // 32,768 B  (KT*OUTW == 8192 both modes)
    __shared__ float sacc[256];          // mode 3 partial output

    const int tid = threadIdx.x;
    const int cg  = tid % CG;
    const int ns  = tid / CG;

    if constexpr (MODE == 3) sacc[tid] = 0.0f;   // before first barrier

    for (int tile = blockIdx.x; tile < NTILES; tile += gridDim.x) {
        const int row0 = tile * NTILE;
        __syncthreads();

        for (int i = tid; i < NTILE * 32; i += 256) {
            const int r  = i >> 5;
            const int kq = i & 31;
            const int gr = row0 + r;
            float4 v = make_float4(0.f, 0.f, 0.f, 0.f);
            if (gr < NMROWS)
                v = reinterpret_cast<const float4*>(A + (size_t)gr * NH)[kq];
            *reinterpret_cast<float4*>(&sh[r * HSTR + kq * 4]) = v;
        }

        float acc[RPS][4];
        #pragma unroll
        for (int t = 0; t < RPS; ++t) {
            acc[t][0] = 0.f; acc[t][1] = 0.f; acc[t][2] = 0.f; acc[t][3] = 0.f;
        }

        for (int kb = 0; kb < NKB; ++kb) {
            __syncthreads();
            const float* Wk = W + kb * KT * OUTW;
            for (int i = tid * 4; i < KT * OUTW; i += 1024)
                *reinterpret_cast<float4*>(&sW[i]) = *reinterpret_cast<const float4*>(Wk + i);
            __syncthreads();

            for (int k = 0; k < KT; ++k) {
                const float4 w = *reinterpret_cast<const float4*>(&sW[k * OUTW + cg * 4]);
                #pragma unroll
                for (int t = 0; t < RPS; ++t) {
                    const float hv = sh[(ns * RPS + t) * HSTR + kb * KT + k];
                    acc[t][0] += hv * w.x; acc[t][1] += hv * w.y;
                    acc[t][2] += hv * w.z; acc[t][3] += hv * w.w;
                }
            }
        }

        const int ch = cg * 4;
        #pragma unroll
        for (int t = 0; t < RPS; ++t) {
            const int gr = row0 + ns * RPS + t;
            if (gr >= NMROWS) continue;
            float v0 = acc[t][0] + bias[ch + 0];
            float v1 = acc[t][1] + bias[ch + 1];
            float v2 = acc[t][2] + bias[ch + 2];
            float v3 = acc[t][3] + bias[ch + 3];
            if constexpr (MODE == 0) {
                float4 o = make_float4(gelu_f(v0), gelu_f(v1), gelu_f(v2), gelu_f(v3));
                *reinterpret_cast<float4*>(&outp[(size_t)gr * NH + ch]) = o;
            } else if constexpr (MODE == 1) {
                float4 cur = *reinterpret_cast<const float4*>(&outp[(size_t)gr * NH + ch]);
                cur.x += gelu_f(v0); cur.y += gelu_f(v1);
                cur.z += gelu_f(v2); cur.w += gelu_f(v3);
                *reinterpret_cast<float4*>(&outp[(size_t)gr * NH + ch]) = cur;
            } else if constexpr (MODE == 2) {
                float4 o = make_float4(fmaxf(v0, 0.f), fmaxf(v1, 0.f),
                                       fmaxf(v2, 0.f), fmaxf(v3, 0.f));
                *reinterpret_cast<float4*>(&outp[(size_t)gr * NH + ch]) = o;
            } else {
                const float w = nm[gr];
                const int c = gr / NNODES;
                atomicAdd(&sacc[c * 64 + ch + 0], v0 * w);
                atomicAdd(&sacc[c * 64 + ch + 1], v1 * w);
                atomicAdd(&sacc[c * 64 + ch + 2], v2 * w);
                atomicAdd(&sacc[c * 64 + ch + 3], v3 * w);
            }
        }
    }

    if constexpr (MODE == 3) {
        __syncthreads();
        atomicAdd(&outp[tid], sacc[tid]);   // outp = out_acc[256]
    }
}

// -------------------------------------------------------------------------
__global__ __launch_bounds__(256) void final_kernel(
    const float* __restrict__ acc, const float* __restrict__ nm,
    float* __restrict__ outp)
{
    const int tid  = threadIdx.x;
    const int c    = tid >> 6;
    const int lane = tid & 63;
    float s = 0.f;
    for (int n = lane; n < NNODES; n += 64) s += nm[c * NNODES + n];
    #pragma unroll
    for (int off = 32; off > 0; off >>= 1) s += __shfl_down(s, off, 64);
    const float denom = __shfl(s, 0, 64);
    outp[tid] = acc[tid] / denom;
}

extern "C" void kernel_launch(void* const* d_in, const int* in_sizes, int n_in,
                              void* d_out, int out_size, void* d_ws, size_t ws_size,
                              hipStream_t stream) {
    const float* x    = (const float*)d_in[0];
    const float* nm   = (const float*)d_in[1];
    const float* ea   = (const float*)d_in[2];
    const float* bW   = (const float*)d_in[3];
    const float* bb   = (const float*)d_in[4];
    const float* cW1  = (const float*)d_in[5];
    const float* cb1  = (const float*)d_in[6];
    const float* cW2  = (const float*)d_in[7];
    const float* cb2  = (const float*)d_in[8];
    const float* eps  = (const float*)d_in[9];
    const float* mW1  = (const float*)d_in[10];
    const float* mb1  = (const float*)d_in[11];
    const float* mW2  = (const float*)d_in[12];
    const float* mb2  = (const float*)d_in[13];
    const int*   ei   = (const int*)d_in[14];

    float* ws   = (float*)d_ws;
    float* xcur = ws;                      // 5,120,000 floats
    float* hbuf = ws + 5120000;            // 5,120,000 floats (h / t alias)
    float* oacc = ws + 10240000;           // 256 floats
    float* ea_s = ws + 10240256;           // 2,560,000 floats (CSR-ordered edge_attr)
    int*   ib   = (int*)(ws + 12800256);
    int*   off  = ib;                      // 10001
    int*   cur  = ib + 10002;              // 10000
    int*   deg  = ib + 20002;              // 10000
    int*   esrc = ib + 30002;              // 160000

    hipMemcpyAsync(xcur, x, (size_t)5120000 * 4, hipMemcpyDeviceToDevice, stream);
    hipMemsetAsync(deg, 0, 10000 * 4, stream);
    hist_kernel<<<(NEDGES + 255) / 256, 256, 0, stream>>>(ei, deg);
    scan_kernel<<<1, 1024, 0, stream>>>(deg, off, cur);
    scatter_kernel<<<(NEDGES + 255) / 256, 256, 0, stream>>>(ei, ea, cur, esrc, ea_s);

    for (int l = 0; l < 3; ++l) {
        agg_kernel<<<2500, 256, 0, stream>>>(xcur, nm, ea_s, bW, bb, off, esrc,
                                             eps, l, hbuf);
        gemm_kernel<0><<<NTILES, 256, 0, stream>>>(hbuf, cW1 + l * 16384,
                                                   cb1 + l * 128, nullptr, hbuf);
        gemm_kernel<1><<<NTILES, 256, 0, stream>>>(hbuf, cW2 + l * 16384,
                                                   cb2 + l * 128, nullptr, xcur);
    }

    gemm_kernel<2><<<NTILES, 256, 0, stream>>>(xcur, mW1, mb1, nullptr, hbuf);
    hipMemsetAsync(oacc, 0, 256 * 4, stream);
    gemm_kernel<3><<<NTILES, 256, 0, stream>>>(hbuf, mW2, mb2, nm, oacc);
    final_kernel<<<1, 256, 0, stream>>>(oacc, nm, (float*)d_out);
}

// Round 8
// 617.415 us; speedup vs baseline: 1.8707x; 1.0053x over previous
//
#include <hip/hip_runtime.h>
#include <hip/hip_bf16.h>
#include <cstddef>
#include <cstdint>

#define NNODES 10000
#define NEDGES 160000
#define NH     128
#define NCOMBO 4
#define NMROWS (NCOMBO * NNODES)              // 40000 rows (combo-major)
#define NTILE  48
#define HSTR   132                            // padded h-tile stride (floats)
#define NTILES ((NMROWS + NTILE - 1) / NTILE) // 834

// Branchless erf-gelu via Abramowitz-Stegun 7.1.26 (|erf err| <= 1.5e-7).
__device__ __forceinline__ float gelu_f(float v) {
    const float u  = v * 0.70710678118654752f;
    float au = __builtin_fabsf(u);
    au = fminf(au, 3.9192f);                       // erf(3.92) = 1 - 1e-8
    const float t  = __builtin_amdgcn_rcpf(__builtin_fmaf(0.3275911f, au, 1.0f));
    const float e  = __builtin_amdgcn_exp2f(au * au * -1.4426950408889634f);
    float p = __builtin_fmaf(1.061405429f, t, -1.453152027f);
    p = __builtin_fmaf(p, t, 1.421413741f);
    p = __builtin_fmaf(p, t, -0.284496736f);
    p = __builtin_fmaf(p, t, 0.254829592f);
    const float erf_abs = 1.0f - p * t * e;        // erf(|u|)
    const float erf_s   = __builtin_copysignf(erf_abs, v);
    return 0.5f * v * (1.0f + erf_s);
}

__device__ __forceinline__ uint16_t f2bf_rne(float f) {
    const uint32_t x = __float_as_uint(f);
    return (uint16_t)((x + 0x7fffu + ((x >> 16) & 1u)) >> 16);
}

// ========================= CSR build (by dst) ============================
__global__ __launch_bounds__(256) void hist_kernel(const int* __restrict__ ei,
                                                   int* __restrict__ deg) {
    const int e = blockIdx.x * 256 + threadIdx.x;
    if (e < NEDGES) atomicAdd(&deg[ei[NEDGES + e]], 1);
}

__global__ __launch_bounds__(1024) void scan_kernel(const int* __restrict__ deg,
                                                    int* __restrict__ off,
                                                    int* __restrict__ cursor) {
    __shared__ int ssum[1024];
    const int tid  = threadIdx.x;
    const int base = tid * 10;
    int loc[10];
    int s = 0;
    #pragma unroll
    for (int i = 0; i < 10; ++i) {
        const int idx = base + i;
        loc[i] = s;
        s += (idx < NNODES) ? deg[idx] : 0;
    }
    ssum[tid] = s;
    for (int d = 1; d < 1024; d <<= 1) {
        __syncthreads();
        const int t = (tid >= d) ? ssum[tid - d] : 0;
        __syncthreads();
        ssum[tid] += t;
    }
    __syncthreads();
    const int pref = ssum[tid] - s;
    #pragma unroll
    for (int i = 0; i < 10; ++i) {
        const int idx = base + i;
        if (idx < NNODES) { off[idx] = pref + loc[i]; cursor[idx] = pref + loc[i]; }
    }
    if (tid == 0) off[NNODES] = NEDGES;
}

__global__ __launch_bounds__(256) void scatter_kernel(const int* __restrict__ ei,
                                                      const float* __restrict__ ea,
                                                      int* __restrict__ cursor,
                                                      int* __restrict__ esrc,
                                                      float* __restrict__ ea_s) {
    const int e = blockIdx.x * 256 + threadIdx.x;
    if (e < NEDGES) {
        const int src = ei[e];
        const int dst = ei[NEDGES + e];
        const int pos = atomicAdd(&cursor[dst], 1);
        esrc[pos] = src;
        const float4* s = reinterpret_cast<const float4*>(ea + (size_t)e * 16);
        float4*       d = reinterpret_cast<float4*>(ea_s + (size_t)pos * 16);
        d[0] = s[0]; d[1] = s[1]; d[2] = s[2]; d[3] = s[3];
    }
}

// ============= bond embedding, precomputed once, bf16, CSR order =========
// embq[j*64 + lane] packs channels (2*lane, 2*lane+1) of emb row j.
__global__ __launch_bounds__(256) void emb_kernel(
    const float* __restrict__ ea_s, const float* __restrict__ bW,
    const float* __restrict__ bb, uint32_t* __restrict__ embq)
{
    const int lane = threadIdx.x & 63;
    const int wid  = threadIdx.x >> 6;
    const int c0   = lane * 2;
    float2 wc[16];
    #pragma unroll
    for (int k = 0; k < 16; ++k)
        wc[k] = *reinterpret_cast<const float2*>(&bW[k * 128 + c0]);
    const float2 bbr = *reinterpret_cast<const float2*>(&bb[c0]);

    for (int j = blockIdx.x * 4 + wid; j < NEDGES; j += gridDim.x * 4) {
        const float4* eap = reinterpret_cast<const float4*>(ea_s + (size_t)j * 16);
        const float4 a0 = eap[0], a1 = eap[1], a2 = eap[2], a3 = eap[3];
        float s0 = bbr.x, s1 = bbr.y;
        s0 += a0.x*wc[0].x + a0.y*wc[1].x + a0.z*wc[2].x + a0.w*wc[3].x
            + a1.x*wc[4].x + a1.y*wc[5].x + a1.z*wc[6].x + a1.w*wc[7].x
            + a2.x*wc[8].x + a2.y*wc[9].x + a2.z*wc[10].x + a2.w*wc[11].x
            + a3.x*wc[12].x + a3.y*wc[13].x + a3.z*wc[14].x + a3.w*wc[15].x;
        s1 += a0.x*wc[0].y + a0.y*wc[1].y + a0.z*wc[2].y + a0.w*wc[3].y
            + a1.x*wc[4].y + a1.y*wc[5].y + a1.z*wc[6].y + a1.w*wc[7].y
            + a2.x*wc[8].y + a2.y*wc[9].y + a2.z*wc[10].y + a2.w*wc[11].y
            + a3.x*wc[12].y + a3.y*wc[13].y + a3.z*wc[14].y + a3.w*wc[15].y;
        embq[(size_t)j * 64 + lane] =
            ((uint32_t)f2bf_rne(s1) << 16) | (uint32_t)f2bf_rne(s0);
    }
}

// =============== message passing: 1 wave/node, ch-pair/lane ==============
// hout[c,n,:] = (1+eps)*xsrc[c,n,:] + sum_{CSR j of n} gelu(xsrc[c,src]+emb_j)*m
__global__ __launch_bounds__(256) void agg2_kernel(
    const float* __restrict__ xsrc,   // [4][N][128]
    const float* __restrict__ nm,     // [4][N]
    const uint32_t* __restrict__ embq,// [E][64] packed bf16 pairs
    const int*   __restrict__ off,    // [N+1]
    const int*   __restrict__ esrc,   // [E] CSR src
    const float* __restrict__ epsp, int layer,
    float* __restrict__ hout)         // [4][N][128]
{
    const int lane = threadIdx.x & 63;
    const int wid  = threadIdx.x >> 6;
    const int c0   = lane * 2;
    const float epv = 1.0f + epsp[layer];

    for (int n = blockIdx.x * 4 + wid; n < NNODES; n += gridDim.x * 4) {
        const int j0 = off[n], j1 = off[n + 1];
        float dm[4];
        #pragma unroll
        for (int c = 0; c < 4; ++c) dm[c] = nm[c * NNODES + n];

        float acc[4][2] = {{0.f,0.f},{0.f,0.f},{0.f,0.f},{0.f,0.f}};

        // 1-deep software pipeline
        uint32_t eq_c = 0; float mv_c[4]; float2 xv_c[4];
        if (j0 < j1) {
            const int s = esrc[j0];
            eq_c = embq[(size_t)j0 * 64 + lane];
            #pragma unroll
            for (int c = 0; c < 4; ++c) {
                mv_c[c] = nm[c * NNODES + s] * dm[c];
                xv_c[c] = *reinterpret_cast<const float2*>(
                              &xsrc[((size_t)c * NNODES + s) * NH + c0]);
            }
        }
        for (int j = j0; j < j1; ++j) {
            const uint32_t eq = eq_c;
            float mv[4]; float2 xv[4];
            #pragma unroll
            for (int c = 0; c < 4; ++c) { mv[c] = mv_c[c]; xv[c] = xv_c[c]; }
            if (j + 1 < j1) {
                const int s = esrc[j + 1];
                eq_c = embq[(size_t)(j + 1) * 64 + lane];
                #pragma unroll
                for (int c = 0; c < 4; ++c) {
                    mv_c[c] = nm[c * NNODES + s] * dm[c];
                    xv_c[c] = *reinterpret_cast<const float2*>(
                                  &xsrc[((size_t)c * NNODES + s) * NH + c0]);
                }
            }
            const float e0 = __uint_as_float(eq << 16);
            const float e1 = __uint_as_float(eq & 0xffff0000u);
            #pragma unroll
            for (int c = 0; c < 4; ++c) {
                acc[c][0] += gelu_f(xv[c].x + e0) * mv[c];
                acc[c][1] += gelu_f(xv[c].y + e1) * mv[c];
            }
        }
        #pragma unroll
        for (int c = 0; c < 4; ++c) {
            const float2 xo = *reinterpret_cast<const float2*>(
                                  &xsrc[((size_t)c * NNODES + n) * NH + c0]);
            float2 o;
            o.x = epv * xo.x + acc[c][0];
            o.y = epv * xo.y + acc[c][1];
            *reinterpret_cast<float2*>(&hout[((size_t)c * NNODES + n) * NH + c0]) = o;
        }
    }
}

// ============ fallback agg (round-4 path, used if ws too small) ==========
__global__ __launch_bounds__(256) void agg_kernel(
    const float* __restrict__ xcur, const float* __restrict__ nm,
    const float* __restrict__ ea_s, const float* __restrict__ bW,
    const float* __restrict__ bb, const int* __restrict__ off,
    const int* __restrict__ esrc, const float* __restrict__ epsp, int layer,
    float* __restrict__ hout)
{
    const int tid = threadIdx.x;
    const int h   = tid & 127;
    const int sub = tid >> 7;
    float wc[16];
    #pragma unroll
    for (int k = 0; k < 16; ++k) wc[k] = bW[k * 128 + h];
    const float bbr = bb[h];
    const float epv = 1.0f + epsp[layer];

    for (int n = blockIdx.x * 2 + sub; n < NNODES; n += gridDim.x * 2) {
        float acc0 = 0.f, acc1 = 0.f, acc2 = 0.f, acc3 = 0.f;
        const int j0 = off[n], j1 = off[n + 1];
        const float d0 = nm[0*NNODES+n], d1 = nm[1*NNODES+n];
        const float d2 = nm[2*NNODES+n], d3 = nm[3*NNODES+n];
        for (int j = j0; j < j1; ++j) {
            const int src = esrc[j];
            const float4* eap = reinterpret_cast<const float4*>(ea_s + (size_t)j * 16);
            const float4 a0 = eap[0], a1 = eap[1], a2 = eap[2], a3 = eap[3];
            float emb = bbr;
            emb += a0.x*wc[0] + a0.y*wc[1] + a0.z*wc[2] + a0.w*wc[3];
            emb += a1.x*wc[4] + a1.y*wc[5] + a1.z*wc[6] + a1.w*wc[7];
            emb += a2.x*wc[8] + a2.y*wc[9] + a2.z*wc[10] + a2.w*wc[11];
            emb += a3.x*wc[12] + a3.y*wc[13] + a3.z*wc[14] + a3.w*wc[15];
            const float m0 = nm[0*NNODES+src]*d0, m1 = nm[1*NNODES+src]*d1;
            const float m2 = nm[2*NNODES+src]*d2, m3 = nm[3*NNODES+src]*d3;
            acc0 += gelu_f(xcur[((size_t)0*NNODES+src)*NH+h] + emb) * m0;
            acc1 += gelu_f(xcur[((size_t)1*NNODES+src)*NH+h] + emb) * m1;
            acc2 += gelu_f(xcur[((size_t)2*NNODES+src)*NH+h] + emb) * m2;
            acc3 += gelu_f(xcur[((size_t)3*NNODES+src)*NH+h] + emb) * m3;
        }
        hout[((size_t)0*NNODES+n)*NH+h] = epv * xcur[((size_t)0*NNODES+n)*NH+h] + acc0;
        hout[((size_t)1*NNODES+n)*NH+h] = epv * xcur[((size_t)1*NNODES+n)*NH+h] + acc1;
        hout[((size_t)2*NNODES+n)*NH+h] = epv * xcur[((size_t)2*NNODES+n)*NH+h] + acc2;
        hout[((size_t)3*NNODES+n)*NH+h] = epv * xcur[((size_t)3*NNODES+n)*NH+h] + acc3;
    }
}

// -------------------------------------------------------------------------
// Fused tiled GEMM over [40000,128] rows, k-chunked float4 LDS reads.
// MODE 0: outp = gelu(A@W + b)
// MODE 1: outp = resid + gelu(A@W + b)
// MODE 2: outp = relu(A@W + b)
// MODE 3: out_acc[c] += (A@W + b) * nm[row]   (outp = 256-float accumulator)
// -------------------------------------------------------------------------
template <int MODE>
__global__ __launch_bounds__(256) void gemm_kernel(
    const float* __restrict__ A,
    const float* __restrict__ W,      // [128][OUTW]
    const float* __restrict__ bias,   // [OUTW]
    const float* __restrict__ nm,     // [40000] flat mask (mode 3)
    const float* __restrict__ resid,  // residual base (mode 1)
    float* __restrict__ outp)
{
    constexpr int OUTW = (MODE == 3) ? 64 : 128;
    constexpr int KT   = (MODE == 3) ? 128 : 64;
    constexpr int NKB  = 128 / KT;
    constexpr int CG   = OUTW / 4;
    constexpr int NS   = 256 / CG;
    constexpr int RPS  = NTILE / NS;

    __shared__ float sh[NTILE * HSTR];
    __shared__ float sW[128 * 64];
    __shared__ float sacc[256];

    const int tid = threadIdx.x;
    const int cg  = tid % CG;
    const int ns  = tid / CG;

    if constexpr (MODE == 3) sacc[tid] = 0.0f;

    for (int tile = blockIdx.x; tile < NTILES; tile += gridDim.x) {
        const int row0 = tile * NTILE;
        __syncthreads();

        for (int i = tid; i < NTILE * 32; i += 256) {
            const int r  = i >> 5;
            const int kq = i & 31;
            const int gr = row0 + r;
            float4 v = make_float4(0.f, 0.f, 0.f, 0.f);
            if (gr < NMROWS)
                v = reinterpret_cast<const float4*>(A + (size_t)gr * NH)[kq];
            *reinterpret_cast<float4*>(&sh[r * HSTR + kq * 4]) = v;
        }

        float acc[RPS][4];
        #pragma unroll
        for (int t = 0; t < RPS; ++t) {
            acc[t][0] = 0.f; acc[t][1] = 0.f; acc[t][2] = 0.f; acc[t][3] = 0.f;
        }

        for (int kb = 0; kb < NKB; ++kb) {
            __syncthreads();
            const float* Wk = W + kb * KT * OUTW;
            for (int i = tid * 4; i < KT * OUTW; i += 1024)
                *reinterpret_cast<float4*>(&sW[i]) = *reinterpret_cast<const float4*>(Wk + i);
            __syncthreads();

            #pragma unroll 2
            for (int k4 = 0; k4 < KT / 4; ++k4) {
                float4 w0 = *reinterpret_cast<const float4*>(&sW[(k4*4+0)*OUTW + cg*4]);
                float4 w1 = *reinterpret_cast<const float4*>(&sW[(k4*4+1)*OUTW + cg*4]);
                float4 w2 = *reinterpret_cast<const float4*>(&sW[(k4*4+2)*OUTW + cg*4]);
                float4 w3 = *reinterpret_cast<const float4*>(&sW[(k4*4+3)*OUTW + cg*4]);
                const int kk = kb * KT + k4 * 4;
                #pragma unroll
                for (int t = 0; t < RPS; ++t) {
                    const float4 hv = *reinterpret_cast<const float4*>(
                                          &sh[(ns * RPS + t) * HSTR + kk]);
                    acc[t][0] += hv.x*w0.x + hv.y*w1.x + hv.z*w2.x + hv.w*w3.x;
                    acc[t][1] += hv.x*w0.y + hv.y*w1.y + hv.z*w2.y + hv.w*w3.y;
                    acc[t][2] += hv.x*w0.z + hv.y*w1.z + hv.z*w2.z + hv.w*w3.z;
                    acc[t][3] += hv.x*w0.w + hv.y*w1.w + hv.z*w2.w + hv.w*w3.w;
                }
            }
        }

        const int ch = cg * 4;
        #pragma unroll
        for (int t = 0; t < RPS; ++t) {
            const int gr = row0 + ns * RPS + t;
            if (gr >= NMROWS) continue;
            float v0 = acc[t][0] + bias[ch + 0];
            float v1 = acc[t][1] + bias[ch + 1];
            float v2 = acc[t][2] + bias[ch + 2];
            float v3 = acc[t][3] + bias[ch + 3];
            if constexpr (MODE == 0) {
                float4 o = make_float4(gelu_f(v0), gelu_f(v1), gelu_f(v2), gelu_f(v3));
                *reinterpret_cast<float4*>(&outp[(size_t)gr * NH + ch]) = o;
            } else if constexpr (MODE == 1) {
                float4 r = *reinterpret_cast<const float4*>(&resid[(size_t)gr * NH + ch]);
                r.x += gelu_f(v0); r.y += gelu_f(v1);
                r.z += gelu_f(v2); r.w += gelu_f(v3);
                *reinterpret_cast<float4*>(&outp[(size_t)gr * NH + ch]) = r;
            } else if constexpr (MODE == 2) {
                float4 o = make_float4(fmaxf(v0, 0.f), fmaxf(v1, 0.f),
                                       fmaxf(v2, 0.f), fmaxf(v3, 0.f));
                *reinterpret_cast<float4*>(&outp[(size_t)gr * NH + ch]) = o;
            } else {
                const float w = nm[gr];
                const int c = gr / NNODES;
                atomicAdd(&sacc[c * 64 + ch + 0], v0 * w);
                atomicAdd(&sacc[c * 64 + ch + 1], v1 * w);
                atomicAdd(&sacc[c * 64 + ch + 2], v2 * w);
                atomicAdd(&sacc[c * 64 + ch + 3], v3 * w);
            }
        }
    }

    if constexpr (MODE == 3) {
        __syncthreads();
        atomicAdd(&outp[tid], sacc[tid]);
    }
}

// -------------------------------------------------------------------------
__global__ __launch_bounds__(256) void final_kernel(
    const float* __restrict__ acc, const float* __restrict__ nm,
    float* __restrict__ outp)
{
    const int tid  = threadIdx.x;
    const int c    = tid >> 6;
    const int lane = tid & 63;
    float s = 0.f;
    for (int n = lane; n < NNODES; n += 64) s += nm[c * NNODES + n];
    #pragma unroll
    for (int off = 32; off > 0; off >>= 1) s += __shfl_down(s, off, 64);
    const float denom = __shfl(s, 0, 64);
    outp[tid] = acc[tid] / denom;
}

extern "C" void kernel_launch(void* const* d_in, const int* in_sizes, int n_in,
                              void* d_out, int out_size, void* d_ws, size_t ws_size,
                              hipStream_t stream) {
    const float* x    = (const float*)d_in[0];
    const float* nm   = (const float*)d_in[1];
    const float* ea   = (const float*)d_in[2];
    const float* bW   = (const float*)d_in[3];
    const float* bb   = (const float*)d_in[4];
    const float* cW1  = (const float*)d_in[5];
    const float* cb1  = (const float*)d_in[6];
    const float* cW2  = (const float*)d_in[7];
    const float* cb2  = (const float*)d_in[8];
    const float* eps  = (const float*)d_in[9];
    const float* mW1  = (const float*)d_in[10];
    const float* mb1  = (const float*)d_in[11];
    const float* mW2  = (const float*)d_in[12];
    const float* mb2  = (const float*)d_in[13];
    const int*   ei   = (const int*)d_in[14];

    float* ws = (float*)d_ws;
    const bool big = ws_size >= (size_t)23230260ULL * 4ULL;   // ~93 MB

    if (big) {
        float*    xcur = ws;                         // 5,120,000
        float*    hbuf = ws + 5120000;               // 5,120,000
        float*    oacc = ws + 10240000;              // 256
        float*    ea_s = ws + 10240256;              // 2,560,000
        uint32_t* embq = (uint32_t*)(ws + 12800256); // 10,240,000 dwords
        int*      ib   = (int*)(ws + 23040256);
        int* off = ib; int* cur = ib + 10002; int* deg = ib + 20002;
        int* esrc = ib + 30002;

        hipMemsetAsync(deg, 0, 10000 * 4, stream);
        hist_kernel<<<(NEDGES + 255) / 256, 256, 0, stream>>>(ei, deg);
        scan_kernel<<<1, 1024, 0, stream>>>(deg, off, cur);
        scatter_kernel<<<(NEDGES + 255) / 256, 256, 0, stream>>>(ei, ea, cur, esrc, ea_s);
        emb_kernel<<<10000, 256, 0, stream>>>(ea_s, bW, bb, embq);

        for (int l = 0; l < 3; ++l) {
            const float* xs = (l == 0) ? x : xcur;
            agg2_kernel<<<2500, 256, 0, stream>>>(xs, nm, embq, off, esrc, eps, l, hbuf);
            gemm_kernel<0><<<NTILES, 256, 0, stream>>>(hbuf, cW1 + l * 16384,
                                                       cb1 + l * 128, nullptr, nullptr, hbuf);
            gemm_kernel<1><<<NTILES, 256, 0, stream>>>(hbuf, cW2 + l * 16384,
                                                       cb2 + l * 128, nullptr, xs, xcur);
        }
        gemm_kernel<2><<<NTILES, 256, 0, stream>>>(xcur, mW1, mb1, nullptr, nullptr, hbuf);
        hipMemsetAsync(oacc, 0, 256 * 4, stream);
        gemm_kernel<3><<<NTILES, 256, 0, stream>>>(hbuf, mW2, mb2, nm, nullptr, oacc);
        final_kernel<<<1, 256, 0, stream>>>(oacc, nm, (float*)d_out);
    } else {
        // fallback: round-4 layout/path (~52 MB)
        float* xcur = ws;
        float* hbuf = ws + 5120000;
        float* oacc = ws + 10240000;
        float* ea_s = ws + 10240256;
        int*   ib   = (int*)(ws + 12800256);
        int* off = ib; int* cur = ib + 10002; int* deg = ib + 20002;
        int* esrc = ib + 30002;

        hipMemcpyAsync(xcur, x, (size_t)5120000 * 4, hipMemcpyDeviceToDevice, stream);
        hipMemsetAsync(deg, 0, 10000 * 4, stream);
        hist_kernel<<<(NEDGES + 255) / 256, 256, 0, stream>>>(ei, deg);
        scan_kernel<<<1, 1024, 0, stream>>>(deg, off, cur);
        scatter_kernel<<<(NEDGES + 255) / 256, 256, 0, stream>>>(ei, ea, cur, esrc, ea_s);

        for (int l = 0; l < 3; ++l) {
            agg_kernel<<<2500, 256, 0, stream>>>(xcur, nm, ea_s, bW, bb, off, esrc,
                                                 eps, l, hbuf);
            gemm_kernel<0><<<NTILES, 256, 0, stream>>>(hbuf, cW1 + l * 16384,
                                                       cb1 + l * 128, nullptr, nullptr, hbuf);
            gemm_kernel<1><<<NTILES, 256, 0, stream>>>(hbuf, cW2 + l * 16384,
                                                       cb2 + l * 128, nullptr, xcur, xcur);
        }
        gemm_kernel<2><<<NTILES, 256, 0, stream>>>(xcur, mW1, mb1, nullptr, nullptr, hbuf);
        hipMemsetAsync(oacc, 0, 256 * 4, stream);
        gemm_kernel<3><<<NTILES, 256, 0, stream>>>(hbuf, mW2, mb2, nm, nullptr, oacc);
        final_kernel<<<1, 256, 0, stream>>>(oacc, nm, (float*)d_out);
    }
}

// Round 9
// 552.500 us; speedup vs baseline: 2.0905x; 1.1175x over previous
//
#include <hip/hip_runtime.h>
#include <hip/hip_bf16.h>
#include <cstddef>
#include <cstdint>

#define NNODES 10000
#define NEDGES 160000
#define NH     128
#define NCOMBO 4
#define NMROWS (NCOMBO * NNODES)              // 40000 rows (combo-major)
#define FTILE  32                             // fused-GEMM tile rows
#define HSTR   132                            // padded LDS row stride (floats)
#define FTILES (NMROWS / FTILE)               // 1250

// Branchless erf-gelu via Abramowitz-Stegun 7.1.26 (|erf err| <= 1.5e-7).
__device__ __forceinline__ float gelu_f(float v) {
    const float u  = v * 0.70710678118654752f;
    float au = __builtin_fabsf(u);
    au = fminf(au, 3.9192f);                       // erf(3.92) = 1 - 1e-8
    const float t  = __builtin_amdgcn_rcpf(__builtin_fmaf(0.3275911f, au, 1.0f));
    const float e  = __builtin_amdgcn_exp2f(au * au * -1.4426950408889634f);
    float p = __builtin_fmaf(1.061405429f, t, -1.453152027f);
    p = __builtin_fmaf(p, t, 1.421413741f);
    p = __builtin_fmaf(p, t, -0.284496736f);
    p = __builtin_fmaf(p, t, 0.254829592f);
    const float erf_abs = 1.0f - p * t * e;        // erf(|u|)
    const float erf_s   = __builtin_copysignf(erf_abs, v);
    return 0.5f * v * (1.0f + erf_s);
}

__device__ __forceinline__ uint16_t f2bf_rne(float f) {
    const uint32_t x = __float_as_uint(f);
    return (uint16_t)((x + 0x7fffu + ((x >> 16) & 1u)) >> 16);
}

// ========================= CSR build (by dst) ============================
__global__ __launch_bounds__(256) void hist_kernel(const int* __restrict__ ei,
                                                   int* __restrict__ deg) {
    const int e = blockIdx.x * 256 + threadIdx.x;
    if (e < NEDGES) atomicAdd(&deg[ei[NEDGES + e]], 1);
}

__global__ __launch_bounds__(1024) void scan_kernel(const int* __restrict__ deg,
                                                    int* __restrict__ off,
                                                    int* __restrict__ cursor) {
    __shared__ int ssum[1024];
    const int tid  = threadIdx.x;
    const int base = tid * 10;
    int loc[10];
    int s = 0;
    #pragma unroll
    for (int i = 0; i < 10; ++i) {
        const int idx = base + i;
        loc[i] = s;
        s += (idx < NNODES) ? deg[idx] : 0;
    }
    ssum[tid] = s;
    for (int d = 1; d < 1024; d <<= 1) {
        __syncthreads();
        const int t = (tid >= d) ? ssum[tid - d] : 0;
        __syncthreads();
        ssum[tid] += t;
    }
    __syncthreads();
    const int pref = ssum[tid] - s;
    #pragma unroll
    for (int i = 0; i < 10; ++i) {
        const int idx = base + i;
        if (idx < NNODES) { off[idx] = pref + loc[i]; cursor[idx] = pref + loc[i]; }
    }
    if (tid == 0) off[NNODES] = NEDGES;
}

__global__ __launch_bounds__(256) void scatter_kernel(const int* __restrict__ ei,
                                                      const float* __restrict__ ea,
                                                      int* __restrict__ cursor,
                                                      int* __restrict__ esrc,
                                                      float* __restrict__ ea_s) {
    const int e = blockIdx.x * 256 + threadIdx.x;
    if (e < NEDGES) {
        const int src = ei[e];
        const int dst = ei[NEDGES + e];
        const int pos = atomicAdd(&cursor[dst], 1);
        esrc[pos] = src;
        const float4* s = reinterpret_cast<const float4*>(ea + (size_t)e * 16);
        float4*       d = reinterpret_cast<float4*>(ea_s + (size_t)pos * 16);
        d[0] = s[0]; d[1] = s[1]; d[2] = s[2]; d[3] = s[3];
    }
}

// ============= bond embedding, precomputed once, bf16, CSR order =========
// embq[j*64 + lane] packs channels (2*lane, 2*lane+1) of emb row j.
__global__ __launch_bounds__(256) void emb_kernel(
    const float* __restrict__ ea_s, const float* __restrict__ bW,
    const float* __restrict__ bb, uint32_t* __restrict__ embq)
{
    const int lane = threadIdx.x & 63;
    const int wid  = threadIdx.x >> 6;
    const int c0   = lane * 2;
    float2 wc[16];
    #pragma unroll
    for (int k = 0; k < 16; ++k)
        wc[k] = *reinterpret_cast<const float2*>(&bW[k * 128 + c0]);
    const float2 bbr = *reinterpret_cast<const float2*>(&bb[c0]);

    for (int j = blockIdx.x * 4 + wid; j < NEDGES; j += gridDim.x * 4) {
        const float4* eap = reinterpret_cast<const float4*>(ea_s + (size_t)j * 16);
        const float4 a0 = eap[0], a1 = eap[1], a2 = eap[2], a3 = eap[3];
        float s0 = bbr.x, s1 = bbr.y;
        s0 += a0.x*wc[0].x + a0.y*wc[1].x + a0.z*wc[2].x + a0.w*wc[3].x
            + a1.x*wc[4].x + a1.y*wc[5].x + a1.z*wc[6].x + a1.w*wc[7].x
            + a2.x*wc[8].x + a2.y*wc[9].x + a2.z*wc[10].x + a2.w*wc[11].x
            + a3.x*wc[12].x + a3.y*wc[13].x + a3.z*wc[14].x + a3.w*wc[15].x;
        s1 += a0.x*wc[0].y + a0.y*wc[1].y + a0.z*wc[2].y + a0.w*wc[3].y
            + a1.x*wc[4].y + a1.y*wc[5].y + a1.z*wc[6].y + a1.w*wc[7].y
            + a2.x*wc[8].y + a2.y*wc[9].y + a2.z*wc[10].y + a2.w*wc[11].y
            + a3.x*wc[12].y + a3.y*wc[13].y + a3.z*wc[14].y + a3.w*wc[15].y;
        embq[(size_t)j * 64 + lane] =
            ((uint32_t)f2bf_rne(s1) << 16) | (uint32_t)f2bf_rne(s0);
    }
}

// =============== message passing: 1 wave/node, ch-pair/lane ==============
__global__ __launch_bounds__(256) void agg2_kernel(
    const float* __restrict__ xsrc,   // [4][N][128]
    const float* __restrict__ nm,     // [4][N]
    const uint32_t* __restrict__ embq,// [E][64] packed bf16 pairs
    const int*   __restrict__ off,    // [N+1]
    const int*   __restrict__ esrc,   // [E] CSR src
    const float* __restrict__ epsp, int layer,
    float* __restrict__ hout)         // [4][N][128]
{
    const int lane = threadIdx.x & 63;
    const int wid  = threadIdx.x >> 6;
    const int c0   = lane * 2;
    const float epv = 1.0f + epsp[layer];

    for (int n = blockIdx.x * 4 + wid; n < NNODES; n += gridDim.x * 4) {
        const int j0 = off[n], j1 = off[n + 1];
        float dm[4];
        #pragma unroll
        for (int c = 0; c < 4; ++c) dm[c] = nm[c * NNODES + n];

        float acc[4][2] = {{0.f,0.f},{0.f,0.f},{0.f,0.f},{0.f,0.f}};

        uint32_t eq_c = 0; float mv_c[4]; float2 xv_c[4];
        if (j0 < j1) {
            const int s = esrc[j0];
            eq_c = embq[(size_t)j0 * 64 + lane];
            #pragma unroll
            for (int c = 0; c < 4; ++c) {
                mv_c[c] = nm[c * NNODES + s] * dm[c];
                xv_c[c] = *reinterpret_cast<const float2*>(
                              &xsrc[((size_t)c * NNODES + s) * NH + c0]);
            }
        }
        for (int j = j0; j < j1; ++j) {
            const uint32_t eq = eq_c;
            float mv[4]; float2 xv[4];
            #pragma unroll
            for (int c = 0; c < 4; ++c) { mv[c] = mv_c[c]; xv[c] = xv_c[c]; }
            if (j + 1 < j1) {
                const int s = esrc[j + 1];
                eq_c = embq[(size_t)(j + 1) * 64 + lane];
                #pragma unroll
                for (int c = 0; c < 4; ++c) {
                    mv_c[c] = nm[c * NNODES + s] * dm[c];
                    xv_c[c] = *reinterpret_cast<const float2*>(
                                  &xsrc[((size_t)c * NNODES + s) * NH + c0]);
                }
            }
            const float e0 = __uint_as_float(eq << 16);
            const float e1 = __uint_as_float(eq & 0xffff0000u);
            #pragma unroll
            for (int c = 0; c < 4; ++c) {
                acc[c][0] += gelu_f(xv[c].x + e0) * mv[c];
                acc[c][1] += gelu_f(xv[c].y + e1) * mv[c];
            }
        }
        #pragma unroll
        for (int c = 0; c < 4; ++c) {
            const float2 xo = *reinterpret_cast<const float2*>(
                                  &xsrc[((size_t)c * NNODES + n) * NH + c0]);
            float2 o;
            o.x = epv * xo.x + acc[c][0];
            o.y = epv * xo.y + acc[c][1];
            *reinterpret_cast<float2*>(&hout[((size_t)c * NNODES + n) * NH + c0]) = o;
        }
    }
}

// ============ fallback agg (round-4 path, used if ws too small) ==========
__global__ __launch_bounds__(256) void agg_kernel(
    const float* __restrict__ xcur, const float* __restrict__ nm,
    const float* __restrict__ ea_s, const float* __restrict__ bW,
    const float* __restrict__ bb, const int* __restrict__ off,
    const int* __restrict__ esrc, const float* __restrict__ epsp, int layer,
    float* __restrict__ hout)
{
    const int tid = threadIdx.x;
    const int h   = tid & 127;
    const int sub = tid >> 7;
    float wc[16];
    #pragma unroll
    for (int k = 0; k < 16; ++k) wc[k] = bW[k * 128 + h];
    const float bbr = bb[h];
    const float epv = 1.0f + epsp[layer];

    for (int n = blockIdx.x * 2 + sub; n < NNODES; n += gridDim.x * 2) {
        float acc0 = 0.f, acc1 = 0.f, acc2 = 0.f, acc3 = 0.f;
        const int j0 = off[n], j1 = off[n + 1];
        const float d0 = nm[0*NNODES+n], d1 = nm[1*NNODES+n];
        const float d2 = nm[2*NNODES+n], d3 = nm[3*NNODES+n];
        for (int j = j0; j < j1; ++j) {
            const int src = esrc[j];
            const float4* eap = reinterpret_cast<const float4*>(ea_s + (size_t)j * 16);
            const float4 a0 = eap[0], a1 = eap[1], a2 = eap[2], a3 = eap[3];
            float emb = bbr;
            emb += a0.x*wc[0] + a0.y*wc[1] + a0.z*wc[2] + a0.w*wc[3];
            emb += a1.x*wc[4] + a1.y*wc[5] + a1.z*wc[6] + a1.w*wc[7];
            emb += a2.x*wc[8] + a2.y*wc[9] + a2.z*wc[10] + a2.w*wc[11];
            emb += a3.x*wc[12] + a3.y*wc[13] + a3.z*wc[14] + a3.w*wc[15];
            const float m0 = nm[0*NNODES+src]*d0, m1 = nm[1*NNODES+src]*d1;
            const float m2 = nm[2*NNODES+src]*d2, m3 = nm[3*NNODES+src]*d3;
            acc0 += gelu_f(xcur[((size_t)0*NNODES+src)*NH+h] + emb) * m0;
            acc1 += gelu_f(xcur[((size_t)1*NNODES+src)*NH+h] + emb) * m1;
            acc2 += gelu_f(xcur[((size_t)2*NNODES+src)*NH+h] + emb) * m2;
            acc3 += gelu_f(xcur[((size_t)3*NNODES+src)*NH+h] + emb) * m3;
        }
        hout[((size_t)0*NNODES+n)*NH+h] = epv * xcur[((size_t)0*NNODES+n)*NH+h] + acc0;
        hout[((size_t)1*NNODES+n)*NH+h] = epv * xcur[((size_t)1*NNODES+n)*NH+h] + acc1;
        hout[((size_t)2*NNODES+n)*NH+h] = epv * xcur[((size_t)2*NNODES+n)*NH+h] + acc2;
        hout[((size_t)3*NNODES+n)*NH+h] = epv * xcur[((size_t)3*NNODES+n)*NH+h] + acc3;
    }
}

// -------------------------------------------------------------------------
// Fused conv pair over [40000,128] rows, FTILE=32 rows/block:
//   t   = gelu(h@W1 + b1)      (t stays in LDS)
//   out = resid + gelu(t@W2 + b2)
// Thread map: cg = tid&31 (4 output ch), ns = tid>>5 (8 row slots x 4 rows).
// Inner loop = round-4 proven form (float4 w + broadcast scalar h).
// -------------------------------------------------------------------------
__global__ __launch_bounds__(256) void conv_fused_kernel(
    const float* __restrict__ h,      // [40000][128]
    const float* __restrict__ resid,  // [40000][128]
    const float* __restrict__ W1, const float* __restrict__ b1,
    const float* __restrict__ W2, const float* __restrict__ b2,
    float* __restrict__ outp)         // [40000][128]
{
    __shared__ float sh[FTILE * HSTR];   // 16,896 B
    __shared__ float st[FTILE * HSTR];   // 16,896 B
    __shared__ float sW[64 * 128];       // 32,768 B

    const int tid = threadIdx.x;
    const int cg  = tid & 31;
    const int ns  = tid >> 5;
    const int ch  = cg * 4;

    for (int tile = blockIdx.x; tile < FTILES; tile += gridDim.x) {
        const int row0 = tile * FTILE;
        __syncthreads();   // protect sh from any stragglers of previous tile

        // stage h tile: 32 rows x 32 float4
        for (int i = tid; i < FTILE * 32; i += 256) {
            const int r  = i >> 5;
            const int kq = i & 31;
            *reinterpret_cast<float4*>(&sh[r * HSTR + kq * 4]) =
                reinterpret_cast<const float4*>(h + (size_t)(row0 + r) * NH)[kq];
        }

        float acc[4][4];
        #pragma unroll
        for (int t = 0; t < 4; ++t) {
            acc[t][0] = 0.f; acc[t][1] = 0.f; acc[t][2] = 0.f; acc[t][3] = 0.f;
        }

        // ---- GEMM1: h @ W1 ----
        for (int kb = 0; kb < 2; ++kb) {
            __syncthreads();
            const float* Wk = W1 + kb * 64 * 128;
            for (int i = tid * 4; i < 64 * 128; i += 1024)
                *reinterpret_cast<float4*>(&sW[i]) = *reinterpret_cast<const float4*>(Wk + i);
            __syncthreads();

            for (int k = 0; k < 64; ++k) {
                const float4 w = *reinterpret_cast<const float4*>(&sW[k * 128 + ch]);
                #pragma unroll
                for (int t = 0; t < 4; ++t) {
                    const float hv = sh[(ns * 4 + t) * HSTR + kb * 64 + k];
                    acc[t][0] += hv * w.x; acc[t][1] += hv * w.y;
                    acc[t][2] += hv * w.z; acc[t][3] += hv * w.w;
                }
            }
        }

        // t = gelu(acc + b1) -> st
        {
            const float4 bv = *reinterpret_cast<const float4*>(&b1[ch]);
            #pragma unroll
            for (int t = 0; t < 4; ++t) {
                float4 o;
                o.x = gelu_f(acc[t][0] + bv.x); o.y = gelu_f(acc[t][1] + bv.y);
                o.z = gelu_f(acc[t][2] + bv.z); o.w = gelu_f(acc[t][3] + bv.w);
                *reinterpret_cast<float4*>(&st[(ns * 4 + t) * HSTR + ch]) = o;
                acc[t][0] = 0.f; acc[t][1] = 0.f; acc[t][2] = 0.f; acc[t][3] = 0.f;
            }
        }

        // ---- GEMM2: t @ W2 ----
        for (int kb = 0; kb < 2; ++kb) {
            __syncthreads();   // st writes complete; previous sW readers done
            const float* Wk = W2 + kb * 64 * 128;
            for (int i = tid * 4; i < 64 * 128; i += 1024)
                *reinterpret_cast<float4*>(&sW[i]) = *reinterpret_cast<const float4*>(Wk + i);
            __syncthreads();

            for (int k = 0; k < 64; ++k) {
                const float4 w = *reinterpret_cast<const float4*>(&sW[k * 128 + ch]);
                #pragma unroll
                for (int t = 0; t < 4; ++t) {
                    const float tv = st[(ns * 4 + t) * HSTR + kb * 64 + k];
                    acc[t][0] += tv * w.x; acc[t][1] += tv * w.y;
                    acc[t][2] += tv * w.z; acc[t][3] += tv * w.w;
                }
            }
        }

        // out = resid + gelu(acc + b2)
        {
            const float4 bv = *reinterpret_cast<const float4*>(&b2[ch]);
            #pragma unroll
            for (int t = 0; t < 4; ++t) {
                const int gr = row0 + ns * 4 + t;
                float4 r = *reinterpret_cast<const float4*>(&resid[(size_t)gr * NH + ch]);
                r.x += gelu_f(acc[t][0] + bv.x); r.y += gelu_f(acc[t][1] + bv.y);
                r.z += gelu_f(acc[t][2] + bv.z); r.w += gelu_f(acc[t][3] + bv.w);
                *reinterpret_cast<float4*>(&outp[(size_t)gr * NH + ch]) = r;
            }
        }
    }
}

// -------------------------------------------------------------------------
// Fused final MLP: t = relu(x@mW1 + b1) (LDS); y = t@mW2 + b2;
// out_acc[c][:] += y * nm[row]  (LDS partial -> one global atomic per thread).
// -------------------------------------------------------------------------
__global__ __launch_bounds__(256) void mlp_fused_kernel(
    const float* __restrict__ x,      // [40000][128]
    const float* __restrict__ W1, const float* __restrict__ b1,
    const float* __restrict__ W2,     // [128][64]
    const float* __restrict__ b2,     // [64]
    const float* __restrict__ nm,     // [40000]
    float* __restrict__ oacc)         // [256]
{
    __shared__ float sh[FTILE * HSTR];
    __shared__ float st[FTILE * HSTR];
    __shared__ float sW[64 * 128];
    __shared__ float sacc[256];

    const int tid = threadIdx.x;
    const int cg  = tid & 31;
    const int ns  = tid >> 5;
    const int ch  = cg * 4;
    const int cg2 = tid & 15;          // second GEMM: 16 ch-groups (64 out)
    const int ns2 = tid >> 4;          // 16 row slots x 2 rows
    const int ch2 = cg2 * 4;

    sacc[tid] = 0.0f;

    for (int tile = blockIdx.x; tile < FTILES; tile += gridDim.x) {
        const int row0 = tile * FTILE;
        __syncthreads();

        for (int i = tid; i < FTILE * 32; i += 256) {
            const int r  = i >> 5;
            const int kq = i & 31;
            *reinterpret_cast<float4*>(&sh[r * HSTR + kq * 4]) =
                reinterpret_cast<const float4*>(x + (size_t)(row0 + r) * NH)[kq];
        }

        float acc[4][4];
        #pragma unroll
        for (int t = 0; t < 4; ++t) {
            acc[t][0] = 0.f; acc[t][1] = 0.f; acc[t][2] = 0.f; acc[t][3] = 0.f;
        }

        // ---- GEMM1: x @ mW1 ----
        for (int kb = 0; kb < 2; ++kb) {
            __syncthreads();
            const float* Wk = W1 + kb * 64 * 128;
            for (int i = tid * 4; i < 64 * 128; i += 1024)
                *reinterpret_cast<float4*>(&sW[i]) = *reinterpret_cast<const float4*>(Wk + i);
            __syncthreads();

            for (int k = 0; k < 64; ++k) {
                const float4 w = *reinterpret_cast<const float4*>(&sW[k * 128 + ch]);
                #pragma unroll
                for (int t = 0; t < 4; ++t) {
                    const float hv = sh[(ns * 4 + t) * HSTR + kb * 64 + k];
                    acc[t][0] += hv * w.x; acc[t][1] += hv * w.y;
                    acc[t][2] += hv * w.z; acc[t][3] += hv * w.w;
                }
            }
        }

        // t = relu(acc + b1) -> st
        {
            const float4 bv = *reinterpret_cast<const float4*>(&b1[ch]);
            #pragma unroll
            for (int t = 0; t < 4; ++t) {
                float4 o;
                o.x = fmaxf(acc[t][0] + bv.x, 0.f); o.y = fmaxf(acc[t][1] + bv.y, 0.f);
                o.z = fmaxf(acc[t][2] + bv.z, 0.f); o.w = fmaxf(acc[t][3] + bv.w, 0.f);
                *reinterpret_cast<float4*>(&st[(ns * 4 + t) * HSTR + ch]) = o;
            }
        }

        // ---- GEMM2: t @ mW2 (128 -> 64), full W2 staged (32 KB) ----
        __syncthreads();
        for (int i = tid * 4; i < 128 * 64; i += 1024)
            *reinterpret_cast<float4*>(&sW[i]) = *reinterpret_cast<const float4*>(W2 + i);
        __syncthreads();

        float a2[2][4];
        a2[0][0]=0.f;a2[0][1]=0.f;a2[0][2]=0.f;a2[0][3]=0.f;
        a2[1][0]=0.f;a2[1][1]=0.f;a2[1][2]=0.f;a2[1][3]=0.f;
        for (int k = 0; k < 128; ++k) {
            const float4 w = *reinterpret_cast<const float4*>(&sW[k * 64 + ch2]);
            #pragma unroll
            for (int t = 0; t < 2; ++t) {
                const float tv = st[(ns2 * 2 + t) * HSTR + k];
                a2[t][0] += tv * w.x; a2[t][1] += tv * w.y;
                a2[t][2] += tv * w.z; a2[t][3] += tv * w.w;
            }
        }

        {
            const float4 bv = *reinterpret_cast<const float4*>(&b2[ch2]);
            #pragma unroll
            for (int t = 0; t < 2; ++t) {
                const int gr = row0 + ns2 * 2 + t;
                const float wgt = nm[gr];
                const int c = gr / NNODES;
                atomicAdd(&sacc[c * 64 + ch2 + 0], (a2[t][0] + bv.x) * wgt);
                atomicAdd(&sacc[c * 64 + ch2 + 1], (a2[t][1] + bv.y) * wgt);
                atomicAdd(&sacc[c * 64 + ch2 + 2], (a2[t][2] + bv.z) * wgt);
                atomicAdd(&sacc[c * 64 + ch2 + 3], (a2[t][3] + bv.w) * wgt);
            }
        }
    }

    __syncthreads();
    atomicAdd(&oacc[tid], sacc[tid]);
}

// -------------------------------------------------------------------------
__global__ __launch_bounds__(256) void final_kernel(
    const float* __restrict__ acc, const float* __restrict__ nm,
    float* __restrict__ outp)
{
    const int tid  = threadIdx.x;
    const int c    = tid >> 6;
    const int lane = tid & 63;
    float s = 0.f;
    for (int n = lane; n < NNODES; n += 64) s += nm[c * NNODES + n];
    #pragma unroll
    for (int off = 32; off > 0; off >>= 1) s += __shfl_down(s, off, 64);
    const float denom = __shfl(s, 0, 64);
    outp[tid] = acc[tid] / denom;
}

extern "C" void kernel_launch(void* const* d_in, const int* in_sizes, int n_in,
                              void* d_out, int out_size, void* d_ws, size_t ws_size,
                              hipStream_t stream) {
    const float* x    = (const float*)d_in[0];
    const float* nm   = (const float*)d_in[1];
    const float* ea   = (const float*)d_in[2];
    const float* bW   = (const float*)d_in[3];
    const float* bb   = (const float*)d_in[4];
    const float* cW1  = (const float*)d_in[5];
    const float* cb1  = (const float*)d_in[6];
    const float* cW2  = (const float*)d_in[7];
    const float* cb2  = (const float*)d_in[8];
    const float* eps  = (const float*)d_in[9];
    const float* mW1  = (const float*)d_in[10];
    const float* mb1  = (const float*)d_in[11];
    const float* mW2  = (const float*)d_in[12];
    const float* mb2  = (const float*)d_in[13];
    const int*   ei   = (const int*)d_in[14];

    float* ws = (float*)d_ws;
    const bool big = ws_size >= (size_t)23230260ULL * 4ULL;   // ~93 MB

    if (big) {
        float*    xcur = ws;                         // 5,120,000
        float*    hbuf = ws + 5120000;               // 5,120,000
        float*    oacc = ws + 10240000;              // 256
        float*    ea_s = ws + 10240256;              // 2,560,000
        uint32_t* embq = (uint32_t*)(ws + 12800256); // 10,240,000 dwords
        int*      ib   = (int*)(ws + 23040256);
        int* off = ib; int* cur = ib + 10002; int* deg = ib + 20002;
        int* esrc = ib + 30002;

        hipMemsetAsync(deg, 0, 10000 * 4, stream);
        hist_kernel<<<(NEDGES + 255) / 256, 256, 0, stream>>>(ei, deg);
        scan_kernel<<<1, 1024, 0, stream>>>(deg, off, cur);
        scatter_kernel<<<(NEDGES + 255) / 256, 256, 0, stream>>>(ei, ea, cur, esrc, ea_s);
        emb_kernel<<<10000, 256, 0, stream>>>(ea_s, bW, bb, embq);

        for (int l = 0; l < 3; ++l) {
            const float* xs = (l == 0) ? x : xcur;
            agg2_kernel<<<2500, 256, 0, stream>>>(xs, nm, embq, off, esrc, eps, l, hbuf);
            conv_fused_kernel<<<FTILES, 256, 0, stream>>>(hbuf, xs, cW1 + l * 16384,
                                                          cb1 + l * 128, cW2 + l * 16384,
                                                          cb2 + l * 128, xcur);
        }
        hipMemsetAsync(oacc, 0, 256 * 4, stream);
        mlp_fused_kernel<<<FTILES, 256, 0, stream>>>(xcur, mW1, mb1, mW2, mb2, nm, oacc);
        final_kernel<<<1, 256, 0, stream>>>(oacc, nm, (float*)d_out);
    } else {
        // fallback: round-4 agg (no embq) + fused GEMMs (~52 MB)
        float* xcur = ws;
        float* hbuf = ws + 5120000;
        float* oacc = ws + 10240000;
        float* ea_s = ws + 10240256;
        int*   ib   = (int*)(ws + 12800256);
        int* off = ib; int* cur = ib + 10002; int* deg = ib + 20002;
        int* esrc = ib + 30002;

        hipMemsetAsync(deg, 0, 10000 * 4, stream);
        hist_kernel<<<(NEDGES + 255) / 256, 256, 0, stream>>>(ei, deg);
        scan_kernel<<<1, 1024, 0, stream>>>(deg, off, cur);
        scatter_kernel<<<(NEDGES + 255) / 256, 256, 0, stream>>>(ei, ea, cur, esrc, ea_s);

        for (int l = 0; l < 3; ++l) {
            const float* xs = (l == 0) ? x : xcur;
            agg_kernel<<<2500, 256, 0, stream>>>(xs, nm, ea_s, bW, bb, off, esrc,
                                                 eps, l, hbuf);
            conv_fused_kernel<<<FTILES, 256, 0, stream>>>(hbuf, xs, cW1 + l * 16384,
                                                          cb1 + l * 128, cW2 + l * 16384,
                                                          cb2 + l * 128, xcur);
        }
        hipMemsetAsync(oacc, 0, 256 * 4, stream);
        mlp_fused_kernel<<<FTILES, 256, 0, stream>>>(xcur, mW1, mb1, mW2, mb2, nm, oacc);
        final_kernel<<<1, 256, 0, stream>>>(oacc, nm, (float*)d_out);
    }
}

// Round 10
// 458.156 us; speedup vs baseline: 2.5210x; 1.2059x over previous
//
#include <hip/hip_runtime.h>
#include <hip/hip_bf16.h>
#include <cstddef>
#include <cstdint>

#define NNODES 10000
#define NEDGES 160000
#define NH     128
#define NCOMBO 4
#define NMROWS (NCOMBO * NNODES)              // 40000 rows (combo-major)
#define FTILE  32                             // rows per conv/mlp tile
#define HSTR   132                            // fp32 LDS row stride (floats)
#define SSTR   136                            // bf16 LDS row stride (shorts) = 272B
#define FTILES (NMROWS / FTILE)               // 1250

typedef __attribute__((ext_vector_type(8))) short short8v;   // 8 bf16 (4 VGPR)
typedef __attribute__((ext_vector_type(4))) float f32x4;     // MFMA accumulator

// Branchless erf-gelu via Abramowitz-Stegun 7.1.26 (|erf err| <= 1.5e-7).
__device__ __forceinline__ float gelu_f(float v) {
    const float u  = v * 0.70710678118654752f;
    float au = __builtin_fabsf(u);
    au = fminf(au, 3.9192f);
    const float t  = __builtin_amdgcn_rcpf(__builtin_fmaf(0.3275911f, au, 1.0f));
    const float e  = __builtin_amdgcn_exp2f(au * au * -1.4426950408889634f);
    float p = __builtin_fmaf(1.061405429f, t, -1.453152027f);
    p = __builtin_fmaf(p, t, 1.421413741f);
    p = __builtin_fmaf(p, t, -0.284496736f);
    p = __builtin_fmaf(p, t, 0.254829592f);
    const float erf_abs = 1.0f - p * t * e;
    const float erf_s   = __builtin_copysignf(erf_abs, v);
    return 0.5f * v * (1.0f + erf_s);
}

__device__ __forceinline__ uint16_t f2bf_rne(float f) {
    const uint32_t x = __float_as_uint(f);
    return (uint16_t)((x + 0x7fffu + ((x >> 16) & 1u)) >> 16);
}

// ========================= CSR build (by dst) ============================
__global__ __launch_bounds__(256) void hist_kernel(const int* __restrict__ ei,
                                                   int* __restrict__ deg) {
    const int e = blockIdx.x * 256 + threadIdx.x;
    if (e < NEDGES) atomicAdd(&deg[ei[NEDGES + e]], 1);
}

__global__ __launch_bounds__(1024) void scan_kernel(const int* __restrict__ deg,
                                                    int* __restrict__ off,
                                                    int* __restrict__ cursor) {
    __shared__ int ssum[1024];
    const int tid  = threadIdx.x;
    const int base = tid * 10;
    int loc[10];
    int s = 0;
    #pragma unroll
    for (int i = 0; i < 10; ++i) {
        const int idx = base + i;
        loc[i] = s;
        s += (idx < NNODES) ? deg[idx] : 0;
    }
    ssum[tid] = s;
    for (int d = 1; d < 1024; d <<= 1) {
        __syncthreads();
        const int t = (tid >= d) ? ssum[tid - d] : 0;
        __syncthreads();
        ssum[tid] += t;
    }
    __syncthreads();
    const int pref = ssum[tid] - s;
    #pragma unroll
    for (int i = 0; i < 10; ++i) {
        const int idx = base + i;
        if (idx < NNODES) { off[idx] = pref + loc[i]; cursor[idx] = pref + loc[i]; }
    }
    if (tid == 0) off[NNODES] = NEDGES;
}

__global__ __launch_bounds__(256) void scatter_kernel(const int* __restrict__ ei,
                                                      const float* __restrict__ ea,
                                                      int* __restrict__ cursor,
                                                      int* __restrict__ esrc,
                                                      float* __restrict__ ea_s) {
    const int e = blockIdx.x * 256 + threadIdx.x;
    if (e < NEDGES) {
        const int src = ei[e];
        const int dst = ei[NEDGES + e];
        const int pos = atomicAdd(&cursor[dst], 1);
        esrc[pos] = src;
        const float4* s = reinterpret_cast<const float4*>(ea + (size_t)e * 16);
        float4*       d = reinterpret_cast<float4*>(ea_s + (size_t)pos * 16);
        d[0] = s[0]; d[1] = s[1]; d[2] = s[2]; d[3] = s[3];
    }
}

// ============= bond embedding, precomputed once, bf16, CSR order =========
__global__ __launch_bounds__(256) void emb_kernel(
    const float* __restrict__ ea_s, const float* __restrict__ bW,
    const float* __restrict__ bb, uint32_t* __restrict__ embq)
{
    const int lane = threadIdx.x & 63;
    const int wid  = threadIdx.x >> 6;
    const int c0   = lane * 2;
    float2 wc[16];
    #pragma unroll
    for (int k = 0; k < 16; ++k)
        wc[k] = *reinterpret_cast<const float2*>(&bW[k * 128 + c0]);
    const float2 bbr = *reinterpret_cast<const float2*>(&bb[c0]);

    for (int j = blockIdx.x * 4 + wid; j < NEDGES; j += gridDim.x * 4) {
        const float4* eap = reinterpret_cast<const float4*>(ea_s + (size_t)j * 16);
        const float4 a0 = eap[0], a1 = eap[1], a2 = eap[2], a3 = eap[3];
        float s0 = bbr.x, s1 = bbr.y;
        s0 += a0.x*wc[0].x + a0.y*wc[1].x + a0.z*wc[2].x + a0.w*wc[3].x
            + a1.x*wc[4].x + a1.y*wc[5].x + a1.z*wc[6].x + a1.w*wc[7].x
            + a2.x*wc[8].x + a2.y*wc[9].x + a2.z*wc[10].x + a2.w*wc[11].x
            + a3.x*wc[12].x + a3.y*wc[13].x + a3.z*wc[14].x + a3.w*wc[15].x;
        s1 += a0.x*wc[0].y + a0.y*wc[1].y + a0.z*wc[2].y + a0.w*wc[3].y
            + a1.x*wc[4].y + a1.y*wc[5].y + a1.z*wc[6].y + a1.w*wc[7].y
            + a2.x*wc[8].y + a2.y*wc[9].y + a2.z*wc[10].y + a2.w*wc[11].y
            + a3.x*wc[12].y + a3.y*wc[13].y + a3.z*wc[14].y + a3.w*wc[15].y;
        embq[(size_t)j * 64 + lane] =
            ((uint32_t)f2bf_rne(s1) << 16) | (uint32_t)f2bf_rne(s0);
    }
}

// === weight prep: Wt[n][k] = bf16(W[k][n]) for the 6 conv matrices =======
__global__ __launch_bounds__(256) void wtrans_kernel(
    const float* __restrict__ cW1, const float* __restrict__ cW2,
    short* __restrict__ wbf)
{
    const int gidx = blockIdx.x * 256 + threadIdx.x;   // 6*16384 total
    const int m    = gidx >> 14;                        // matrix 0..5
    const int el   = gidx & 16383;
    const int n    = el >> 7;
    const int k    = el & 127;
    const float* W = (m < 3) ? (cW1 + m * 16384) : (cW2 + (m - 3) * 16384);
    wbf[(size_t)m * 16384 + n * 128 + k] = (short)f2bf_rne(W[k * 128 + n]);
}

// =============== message passing: 1 wave/node, ch-pair/lane ==============
__global__ __launch_bounds__(256) void agg2_kernel(
    const float* __restrict__ xsrc, const float* __restrict__ nm,
    const uint32_t* __restrict__ embq, const int* __restrict__ off,
    const int* __restrict__ esrc, const float* __restrict__ epsp, int layer,
    float* __restrict__ hout)
{
    const int lane = threadIdx.x & 63;
    const int wid  = threadIdx.x >> 6;
    const int c0   = lane * 2;
    const float epv = 1.0f + epsp[layer];

    for (int n = blockIdx.x * 4 + wid; n < NNODES; n += gridDim.x * 4) {
        const int j0 = off[n], j1 = off[n + 1];
        float dm[4];
        #pragma unroll
        for (int c = 0; c < 4; ++c) dm[c] = nm[c * NNODES + n];

        float acc[4][2] = {{0.f,0.f},{0.f,0.f},{0.f,0.f},{0.f,0.f}};

        uint32_t eq_c = 0; float mv_c[4]; float2 xv_c[4];
        if (j0 < j1) {
            const int s = esrc[j0];
            eq_c = embq[(size_t)j0 * 64 + lane];
            #pragma unroll
            for (int c = 0; c < 4; ++c) {
                mv_c[c] = nm[c * NNODES + s] * dm[c];
                xv_c[c] = *reinterpret_cast<const float2*>(
                              &xsrc[((size_t)c * NNODES + s) * NH + c0]);
            }
        }
        for (int j = j0; j < j1; ++j) {
            const uint32_t eq = eq_c;
            float mv[4]; float2 xv[4];
            #pragma unroll
            for (int c = 0; c < 4; ++c) { mv[c] = mv_c[c]; xv[c] = xv_c[c]; }
            if (j + 1 < j1) {
                const int s = esrc[j + 1];
                eq_c = embq[(size_t)(j + 1) * 64 + lane];
                #pragma unroll
                for (int c = 0; c < 4; ++c) {
                    mv_c[c] = nm[c * NNODES + s] * dm[c];
                    xv_c[c] = *reinterpret_cast<const float2*>(
                                  &xsrc[((size_t)c * NNODES + s) * NH + c0]);
                }
            }
            const float e0 = __uint_as_float(eq << 16);
            const float e1 = __uint_as_float(eq & 0xffff0000u);
            #pragma unroll
            for (int c = 0; c < 4; ++c) {
                acc[c][0] += gelu_f(xv[c].x + e0) * mv[c];
                acc[c][1] += gelu_f(xv[c].y + e1) * mv[c];
            }
        }
        #pragma unroll
        for (int c = 0; c < 4; ++c) {
            const float2 xo = *reinterpret_cast<const float2*>(
                                  &xsrc[((size_t)c * NNODES + n) * NH + c0]);
            float2 o;
            o.x = epv * xo.x + acc[c][0];
            o.y = epv * xo.y + acc[c][1];
            *reinterpret_cast<float2*>(&hout[((size_t)c * NNODES + n) * NH + c0]) = o;
        }
    }
}

// ============ fallback agg (round-4 path) ================================
__global__ __launch_bounds__(256) void agg_kernel(
    const float* __restrict__ xcur, const float* __restrict__ nm,
    const float* __restrict__ ea_s, const float* __restrict__ bW,
    const float* __restrict__ bb, const int* __restrict__ off,
    const int* __restrict__ esrc, const float* __restrict__ epsp, int layer,
    float* __restrict__ hout)
{
    const int tid = threadIdx.x;
    const int h   = tid & 127;
    const int sub = tid >> 7;
    float wc[16];
    #pragma unroll
    for (int k = 0; k < 16; ++k) wc[k] = bW[k * 128 + h];
    const float bbr = bb[h];
    const float epv = 1.0f + epsp[layer];

    for (int n = blockIdx.x * 2 + sub; n < NNODES; n += gridDim.x * 2) {
        float acc0 = 0.f, acc1 = 0.f, acc2 = 0.f, acc3 = 0.f;
        const int j0 = off[n], j1 = off[n + 1];
        const float d0 = nm[0*NNODES+n], d1 = nm[1*NNODES+n];
        const float d2 = nm[2*NNODES+n], d3 = nm[3*NNODES+n];
        for (int j = j0; j < j1; ++j) {
            const int src = esrc[j];
            const float4* eap = reinterpret_cast<const float4*>(ea_s + (size_t)j * 16);
            const float4 a0 = eap[0], a1 = eap[1], a2 = eap[2], a3 = eap[3];
            float emb = bbr;
            emb += a0.x*wc[0] + a0.y*wc[1] + a0.z*wc[2] + a0.w*wc[3];
            emb += a1.x*wc[4] + a1.y*wc[5] + a1.z*wc[6] + a1.w*wc[7];
            emb += a2.x*wc[8] + a2.y*wc[9] + a2.z*wc[10] + a2.w*wc[11];
            emb += a3.x*wc[12] + a3.y*wc[13] + a3.z*wc[14] + a3.w*wc[15];
            const float m0 = nm[0*NNODES+src]*d0, m1 = nm[1*NNODES+src]*d1;
            const float m2 = nm[2*NNODES+src]*d2, m3 = nm[3*NNODES+src]*d3;
            acc0 += gelu_f(xcur[((size_t)0*NNODES+src)*NH+h] + emb) * m0;
            acc1 += gelu_f(xcur[((size_t)1*NNODES+src)*NH+h] + emb) * m1;
            acc2 += gelu_f(xcur[((size_t)2*NNODES+src)*NH+h] + emb) * m2;
            acc3 += gelu_f(xcur[((size_t)3*NNODES+src)*NH+h] + emb) * m3;
        }
        hout[((size_t)0*NNODES+n)*NH+h] = epv * xcur[((size_t)0*NNODES+n)*NH+h] + acc0;
        hout[((size_t)1*NNODES+n)*NH+h] = epv * xcur[((size_t)1*NNODES+n)*NH+h] + acc1;
        hout[((size_t)2*NNODES+n)*NH+h] = epv * xcur[((size_t)2*NNODES+n)*NH+h] + acc2;
        hout[((size_t)3*NNODES+n)*NH+h] = epv * xcur[((size_t)3*NNODES+n)*NH+h] + acc3;
    }
}

// -------------------------------------------------------------------------
// MFMA fused conv pair, FTILE=32 rows/block, 4 waves (wave w: cols w*32..+31):
//   t   = gelu(h@W1 + b1)   (bf16, stays in LDS)
//   out = resid + gelu(t@W2 + b2)
// Fragments (16x16x32 bf16): A/B lane l: 8 contig k at (l>>4)*8; row/col l&15.
// C/D: col = l&15, row = (l>>4)*4 + reg  [m89-verified].
// -------------------------------------------------------------------------
__global__ __launch_bounds__(256) void conv_mfma_kernel(
    const float* __restrict__ h,      // [40000][128] fp32
    const float* __restrict__ resid,  // [40000][128] fp32
    const short* __restrict__ W1t,    // [128 n][128 k] bf16 (transposed)
    const float* __restrict__ b1,
    const short* __restrict__ W2t,
    const float* __restrict__ b2,
    float* __restrict__ outp)
{
    __shared__ short sh[FTILE * SSTR];   // 8,704 B  (h tile, bf16)
    __shared__ short st[FTILE * SSTR];   // 8,704 B  (t tile, bf16)
    __shared__ short sw[128 * SSTR];     // 34,816 B (weight tile, bf16)

    const int tid  = threadIdx.x;
    const int lane = tid & 63;
    const int w    = tid >> 6;           // wave 0..3
    const int l15  = lane & 15;
    const int l4   = lane >> 4;          // 0..3
    const int colb = w * 32;
    const int row0 = blockIdx.x * FTILE;

    // ---- stage h tile (fp32 -> bf16) ----
    for (int i = tid; i < FTILE * 32; i += 256) {
        const int r = i >> 5, q = i & 31;
        const float4 v = reinterpret_cast<const float4*>(h + (size_t)(row0 + r) * NH)[q];
        uint2 pk;
        pk.x = ((uint32_t)f2bf_rne(v.y) << 16) | (uint32_t)f2bf_rne(v.x);
        pk.y = ((uint32_t)f2bf_rne(v.w) << 16) | (uint32_t)f2bf_rne(v.z);
        *reinterpret_cast<uint2*>(&sh[r * SSTR + q * 4]) = pk;
    }
    // ---- stage W1t ----
    for (int i = tid; i < 128 * 16; i += 256) {        // 16B chunks
        const int r = i >> 4, c = i & 15;
        *reinterpret_cast<uint4*>(&sw[r * SSTR + c * 8]) =
            *reinterpret_cast<const uint4*>(&W1t[r * 128 + c * 8]);
    }
    __syncthreads();

    // ---- GEMM1: t_acc = h @ W1 ----
    f32x4 a00 = {0,0,0,0}, a01 = {0,0,0,0}, a10 = {0,0,0,0}, a11 = {0,0,0,0};
    #pragma unroll
    for (int s = 0; s < 4; ++s) {
        const int ko = s * 32 + l4 * 8;
        short8v fa0 = *reinterpret_cast<const short8v*>(&sh[(l15)      * SSTR + ko]);
        short8v fa1 = *reinterpret_cast<const short8v*>(&sh[(16 + l15) * SSTR + ko]);
        short8v fb0 = *reinterpret_cast<const short8v*>(&sw[(colb + l15)      * SSTR + ko]);
        short8v fb1 = *reinterpret_cast<const short8v*>(&sw[(colb + 16 + l15) * SSTR + ko]);
        a00 = __builtin_amdgcn_mfma_f32_16x16x32_bf16(fa0, fb0, a00, 0, 0, 0);
        a01 = __builtin_amdgcn_mfma_f32_16x16x32_bf16(fa0, fb1, a01, 0, 0, 0);
        a10 = __builtin_amdgcn_mfma_f32_16x16x32_bf16(fa1, fb0, a10, 0, 0, 0);
        a11 = __builtin_amdgcn_mfma_f32_16x16x32_bf16(fa1, fb1, a11, 0, 0, 0);
    }

    // ---- epilogue1: t = gelu(acc + b1) -> st (bf16) ----
    {
        const float bv0 = b1[colb + l15];
        const float bv1 = b1[colb + 16 + l15];
        #pragma unroll
        for (int j = 0; j < 4; ++j) {
            const int r0 = l4 * 4 + j;
            st[r0 * SSTR + colb + l15]           = (short)f2bf_rne(gelu_f(a00[j] + bv0));
            st[r0 * SSTR + colb + 16 + l15]      = (short)f2bf_rne(gelu_f(a01[j] + bv1));
            st[(16 + r0) * SSTR + colb + l15]    = (short)f2bf_rne(gelu_f(a10[j] + bv0));
            st[(16 + r0) * SSTR + colb + 16 + l15] = (short)f2bf_rne(gelu_f(a11[j] + bv1));
        }
    }
    __syncthreads();   // st complete; sw readers done

    // ---- stage W2t ----
    for (int i = tid; i < 128 * 16; i += 256) {
        const int r = i >> 4, c = i & 15;
        *reinterpret_cast<uint4*>(&sw[r * SSTR + c * 8]) =
            *reinterpret_cast<const uint4*>(&W2t[r * 128 + c * 8]);
    }
    __syncthreads();

    // ---- GEMM2: u = t @ W2 ----
    a00 = {0,0,0,0}; a01 = {0,0,0,0}; a10 = {0,0,0,0}; a11 = {0,0,0,0};
    #pragma unroll
    for (int s = 0; s < 4; ++s) {
        const int ko = s * 32 + l4 * 8;
        short8v fa0 = *reinterpret_cast<const short8v*>(&st[(l15)      * SSTR + ko]);
        short8v fa1 = *reinterpret_cast<const short8v*>(&st[(16 + l15) * SSTR + ko]);
        short8v fb0 = *reinterpret_cast<const short8v*>(&sw[(colb + l15)      * SSTR + ko]);
        short8v fb1 = *reinterpret_cast<const short8v*>(&sw[(colb + 16 + l15) * SSTR + ko]);
        a00 = __builtin_amdgcn_mfma_f32_16x16x32_bf16(fa0, fb0, a00, 0, 0, 0);
        a01 = __builtin_amdgcn_mfma_f32_16x16x32_bf16(fa0, fb1, a01, 0, 0, 0);
        a10 = __builtin_amdgcn_mfma_f32_16x16x32_bf16(fa1, fb0, a10, 0, 0, 0);
        a11 = __builtin_amdgcn_mfma_f32_16x16x32_bf16(fa1, fb1, a11, 0, 0, 0);
    }

    // ---- epilogue2: out = resid + gelu(acc + b2) ----
    {
        const float bv0 = b2[colb + l15];
        const float bv1 = b2[colb + 16 + l15];
        #pragma unroll
        for (int j = 0; j < 4; ++j) {
            const int r0 = row0 + l4 * 4 + j;
            const int r1 = r0 + 16;
            const size_t o00 = (size_t)r0 * NH + colb + l15;
            const size_t o01 = (size_t)r0 * NH + colb + 16 + l15;
            const size_t o10 = (size_t)r1 * NH + colb + l15;
            const size_t o11 = (size_t)r1 * NH + colb + 16 + l15;
            outp[o00] = resid[o00] + gelu_f(a00[j] + bv0);
            outp[o01] = resid[o01] + gelu_f(a01[j] + bv1);
            outp[o10] = resid[o10] + gelu_f(a10[j] + bv0);
            outp[o11] = resid[o11] + gelu_f(a11[j] + bv1);
        }
    }
}

// -------------------------------------------------------------------------
// Fused final MLP (fp32): t = relu(x@mW1+b1) (LDS); y = t@mW2+b2;
// oacc[c][:] += y * nm[row].
// -------------------------------------------------------------------------
__global__ __launch_bounds__(256) void mlp_fused_kernel(
    const float* __restrict__ x,
    const float* __restrict__ W1, const float* __restrict__ b1,
    const float* __restrict__ W2, const float* __restrict__ b2,
    const float* __restrict__ nm, float* __restrict__ oacc)
{
    __shared__ float sh[FTILE * HSTR];
    __shared__ float st[FTILE * HSTR];
    __shared__ float sW[64 * 128];
    __shared__ float sacc[256];

    const int tid = threadIdx.x;
    const int cg  = tid & 31;
    const int ns  = tid >> 5;
    const int ch  = cg * 4;
    const int cg2 = tid & 15;
    const int ns2 = tid >> 4;
    const int ch2 = cg2 * 4;

    sacc[tid] = 0.0f;

    for (int tile = blockIdx.x; tile < FTILES; tile += gridDim.x) {
        const int row0 = tile * FTILE;
        __syncthreads();

        for (int i = tid; i < FTILE * 32; i += 256) {
            const int r  = i >> 5;
            const int kq = i & 31;
            *reinterpret_cast<float4*>(&sh[r * HSTR + kq * 4]) =
                reinterpret_cast<const float4*>(x + (size_t)(row0 + r) * NH)[kq];
        }

        float acc[4][4];
        #pragma unroll
        for (int t = 0; t < 4; ++t) {
            acc[t][0] = 0.f; acc[t][1] = 0.f; acc[t][2] = 0.f; acc[t][3] = 0.f;
        }

        for (int kb = 0; kb < 2; ++kb) {
            __syncthreads();
            const float* Wk = W1 + kb * 64 * 128;
            for (int i = tid * 4; i < 64 * 128; i += 1024)
                *reinterpret_cast<float4*>(&sW[i]) = *reinterpret_cast<const float4*>(Wk + i);
            __syncthreads();

            for (int k = 0; k < 64; ++k) {
                const float4 w = *reinterpret_cast<const float4*>(&sW[k * 128 + ch]);
                #pragma unroll
                for (int t = 0; t < 4; ++t) {
                    const float hv = sh[(ns * 4 + t) * HSTR + kb * 64 + k];
                    acc[t][0] += hv * w.x; acc[t][1] += hv * w.y;
                    acc[t][2] += hv * w.z; acc[t][3] += hv * w.w;
                }
            }
        }

        {
            const float4 bv = *reinterpret_cast<const float4*>(&b1[ch]);
            #pragma unroll
            for (int t = 0; t < 4; ++t) {
                float4 o;
                o.x = fmaxf(acc[t][0] + bv.x, 0.f); o.y = fmaxf(acc[t][1] + bv.y, 0.f);
                o.z = fmaxf(acc[t][2] + bv.z, 0.f); o.w = fmaxf(acc[t][3] + bv.w, 0.f);
                *reinterpret_cast<float4*>(&st[(ns * 4 + t) * HSTR + ch]) = o;
            }
        }

        __syncthreads();
        for (int i = tid * 4; i < 128 * 64; i += 1024)
            *reinterpret_cast<float4*>(&sW[i]) = *reinterpret_cast<const float4*>(W2 + i);
        __syncthreads();

        float a2[2][4];
        a2[0][0]=0.f;a2[0][1]=0.f;a2[0][2]=0.f;a2[0][3]=0.f;
        a2[1][0]=0.f;a2[1][1]=0.f;a2[1][2]=0.f;a2[1][3]=0.f;
        for (int k = 0; k < 128; ++k) {
            const float4 w = *reinterpret_cast<const float4*>(&sW[k * 64 + ch2]);
            #pragma unroll
            for (int t = 0; t < 2; ++t) {
                const float tv = st[(ns2 * 2 + t) * HSTR + k];
                a2[t][0] += tv * w.x; a2[t][1] += tv * w.y;
                a2[t][2] += tv * w.z; a2[t][3] += tv * w.w;
            }
        }

        {
            const float4 bv = *reinterpret_cast<const float4*>(&b2[ch2]);
            #pragma unroll
            for (int t = 0; t < 2; ++t) {
                const int gr = row0 + ns2 * 2 + t;
                const float wgt = nm[gr];
                const int c = gr / NNODES;
                atomicAdd(&sacc[c * 64 + ch2 + 0], (a2[t][0] + bv.x) * wgt);
                atomicAdd(&sacc[c * 64 + ch2 + 1], (a2[t][1] + bv.y) * wgt);
                atomicAdd(&sacc[c * 64 + ch2 + 2], (a2[t][2] + bv.z) * wgt);
                atomicAdd(&sacc[c * 64 + ch2 + 3], (a2[t][3] + bv.w) * wgt);
            }
        }
    }

    __syncthreads();
    atomicAdd(&oacc[tid], sacc[tid]);
}

// -------------------------------------------------------------------------
__global__ __launch_bounds__(256) void final_kernel(
    const float* __restrict__ acc, const float* __restrict__ nm,
    float* __restrict__ outp)
{
    const int tid  = threadIdx.x;
    const int c    = tid >> 6;
    const int lane = tid & 63;
    float s = 0.f;
    for (int n = lane; n < NNODES; n += 64) s += nm[c * NNODES + n];
    #pragma unroll
    for (int off = 32; off > 0; off >>= 1) s += __shfl_down(s, off, 64);
    const float denom = __shfl(s, 0, 64);
    outp[tid] = acc[tid] / denom;
}

extern "C" void kernel_launch(void* const* d_in, const int* in_sizes, int n_in,
                              void* d_out, int out_size, void* d_ws, size_t ws_size,
                              hipStream_t stream) {
    const float* x    = (const float*)d_in[0];
    const float* nm   = (const float*)d_in[1];
    const float* ea   = (const float*)d_in[2];
    const float* bW   = (const float*)d_in[3];
    const float* bb   = (const float*)d_in[4];
    const float* cW1  = (const float*)d_in[5];
    const float* cb1  = (const float*)d_in[6];
    const float* cW2  = (const float*)d_in[7];
    const float* cb2  = (const float*)d_in[8];
    const float* eps  = (const float*)d_in[9];
    const float* mW1  = (const float*)d_in[10];
    const float* mb1  = (const float*)d_in[11];
    const float* mW2  = (const float*)d_in[12];
    const float* mb2  = (const float*)d_in[13];
    const int*   ei   = (const int*)d_in[14];

    float* ws = (float*)d_ws;
    const bool big = ws_size >= (size_t)23230260ULL * 4ULL;   // ~93 MB

    if (big) {
        float*    xcur = ws;                         // 5,120,000
        float*    hbuf = ws + 5120000;               // 5,120,000
        float*    oacc = ws + 10240000;              // 256
        float*    ea_s = ws + 10240256;              // 2,560,000 (dead after emb)
        short*    wbf  = (short*)ea_s;               // 6*16384 bf16 (aliases ea_s)
        uint32_t* embq = (uint32_t*)(ws + 12800256); // 10,240,000 dwords
        int*      ib   = (int*)(ws + 23040256);
        int* off = ib; int* cur = ib + 10002; int* deg = ib + 20002;
        int* esrc = ib + 30002;

        hipMemsetAsync(deg, 0, 10000 * 4, stream);
        hist_kernel<<<(NEDGES + 255) / 256, 256, 0, stream>>>(ei, deg);
        scan_kernel<<<1, 1024, 0, stream>>>(deg, off, cur);
        scatter_kernel<<<(NEDGES + 255) / 256, 256, 0, stream>>>(ei, ea, cur, esrc, ea_s);
        emb_kernel<<<10000, 256, 0, stream>>>(ea_s, bW, bb, embq);
        wtrans_kernel<<<384, 256, 0, stream>>>(cW1, cW2, wbf);   // after emb: ea_s dead

        for (int l = 0; l < 3; ++l) {
            const float* xs = (l == 0) ? x : xcur;
            agg2_kernel<<<2500, 256, 0, stream>>>(xs, nm, embq, off, esrc, eps, l, hbuf);
            conv_mfma_kernel<<<FTILES, 256, 0, stream>>>(hbuf, xs,
                wbf + (size_t)l * 16384, cb1 + l * 128,
                wbf + (size_t)(3 + l) * 16384, cb2 + l * 128, xcur);
        }
        hipMemsetAsync(oacc, 0, 256 * 4, stream);
        mlp_fused_kernel<<<FTILES, 256, 0, stream>>>(xcur, mW1, mb1, mW2, mb2, nm, oacc);
        final_kernel<<<1, 256, 0, stream>>>(oacc, nm, (float*)d_out);
    } else {
        // fallback (~52.2 MB): round-4 agg + MFMA conv (wbf after esrc, 16B-aligned)
        float* xcur = ws;
        float* hbuf = ws + 5120000;
        float* oacc = ws + 10240000;
        float* ea_s = ws + 10240256;
        int*   ib   = (int*)(ws + 12800256);
        int* off = ib; int* cur = ib + 10002; int* deg = ib + 20002;
        int* esrc = ib + 30002;
        short* wbf = (short*)(ib + 190004);

        hipMemsetAsync(deg, 0, 10000 * 4, stream);
        hist_kernel<<<(NEDGES + 255) / 256, 256, 0, stream>>>(ei, deg);
        scan_kernel<<<1, 1024, 0, stream>>>(deg, off, cur);
        scatter_kernel<<<(NEDGES + 255) / 256, 256, 0, stream>>>(ei, ea, cur, esrc, ea_s);
        wtrans_kernel<<<384, 256, 0, stream>>>(cW1, cW2, wbf);

        for (int l = 0; l < 3; ++l) {
            const float* xs = (l == 0) ? x : xcur;
            agg_kernel<<<2500, 256, 0, stream>>>(xs, nm, ea_s, bW, bb, off, esrc,
                                                 eps, l, hbuf);
            conv_mfma_kernel<<<FTILES, 256, 0, stream>>>(hbuf, xs,
                wbf + (size_t)l * 16384, cb1 + l * 128,
                wbf + (size_t)(3 + l) * 16384, cb2 + l * 128, xcur);
        }
        hipMemsetAsync(oacc, 0, 256 * 4, stream);
        mlp_fused_kernel<<<FTILES, 256, 0, stream>>>(xcur, mW1, mb1, mW2, mb2, nm, oacc);
        final_kernel<<<1, 256, 0, stream>>>(oacc, nm, (float*)d_out);
    }
}

// Round 11
// 452.435 us; speedup vs baseline: 2.5529x; 1.0126x over previous
//
#include <hip/hip_runtime.h>
#include <hip/hip_bf16.h>
#include <cstddef>
#include <cstdint>

#define NNODES 10000
#define NEDGES 160000
#define NH     128
#define NCOMBO 4
#define NMROWS (NCOMBO * NNODES)              // 40000 rows (combo-major)
#define FTILE  32                             // rows per conv/mlp tile
#define SSTR   136                            // bf16 LDS row stride (shorts) = 272B
#define FTILES (NMROWS / FTILE)               // 1250

typedef __attribute__((ext_vector_type(8))) short short8v;   // 8 bf16 (4 VGPR)
typedef __attribute__((ext_vector_type(4))) float f32x4;     // MFMA accumulator

// Branchless erf-gelu via Abramowitz-Stegun 7.1.26 (|erf err| <= 1.5e-7).
__device__ __forceinline__ float gelu_f(float v) {
    const float u  = v * 0.70710678118654752f;
    float au = __builtin_fabsf(u);
    au = fminf(au, 3.9192f);
    const float t  = __builtin_amdgcn_rcpf(__builtin_fmaf(0.3275911f, au, 1.0f));
    const float e  = __builtin_amdgcn_exp2f(au * au * -1.4426950408889634f);
    float p = __builtin_fmaf(1.061405429f, t, -1.453152027f);
    p = __builtin_fmaf(p, t, 1.421413741f);
    p = __builtin_fmaf(p, t, -0.284496736f);
    p = __builtin_fmaf(p, t, 0.254829592f);
    const float erf_abs = 1.0f - p * t * e;
    const float erf_s   = __builtin_copysignf(erf_abs, v);
    return 0.5f * v * (1.0f + erf_s);
}

__device__ __forceinline__ uint16_t f2bf_rne(float f) {
    const uint32_t x = __float_as_uint(f);
    return (uint16_t)((x + 0x7fffu + ((x >> 16) & 1u)) >> 16);
}

// ========================= CSR build (by dst) ============================
__global__ __launch_bounds__(256) void hist_kernel(const int* __restrict__ ei,
                                                   int* __restrict__ deg) {
    const int e = blockIdx.x * 256 + threadIdx.x;
    if (e < NEDGES) atomicAdd(&deg[ei[NEDGES + e]], 1);
}

__global__ __launch_bounds__(1024) void scan_kernel(const int* __restrict__ deg,
                                                    int* __restrict__ off,
                                                    int* __restrict__ cursor) {
    __shared__ int ssum[1024];
    const int tid  = threadIdx.x;
    const int base = tid * 10;
    int loc[10];
    int s = 0;
    #pragma unroll
    for (int i = 0; i < 10; ++i) {
        const int idx = base + i;
        loc[i] = s;
        s += (idx < NNODES) ? deg[idx] : 0;
    }
    ssum[tid] = s;
    for (int d = 1; d < 1024; d <<= 1) {
        __syncthreads();
        const int t = (tid >= d) ? ssum[tid - d] : 0;
        __syncthreads();
        ssum[tid] += t;
    }
    __syncthreads();
    const int pref = ssum[tid] - s;
    #pragma unroll
    for (int i = 0; i < 10; ++i) {
        const int idx = base + i;
        if (idx < NNODES) { off[idx] = pref + loc[i]; cursor[idx] = pref + loc[i]; }
    }
    if (tid == 0) off[NNODES] = NEDGES;
}

__global__ __launch_bounds__(256) void scatter_kernel(const int* __restrict__ ei,
                                                      const float* __restrict__ ea,
                                                      int* __restrict__ cursor,
                                                      int* __restrict__ esrc,
                                                      float* __restrict__ ea_s) {
    const int e = blockIdx.x * 256 + threadIdx.x;
    if (e < NEDGES) {
        const int src = ei[e];
        const int dst = ei[NEDGES + e];
        const int pos = atomicAdd(&cursor[dst], 1);
        esrc[pos] = src;
        const float4* s = reinterpret_cast<const float4*>(ea + (size_t)e * 16);
        float4*       d = reinterpret_cast<float4*>(ea_s + (size_t)pos * 16);
        d[0] = s[0]; d[1] = s[1]; d[2] = s[2]; d[3] = s[3];
    }
}

// ============= bond embedding, precomputed once, bf16, CSR order =========
__global__ __launch_bounds__(256) void emb_kernel(
    const float* __restrict__ ea_s, const float* __restrict__ bW,
    const float* __restrict__ bb, uint32_t* __restrict__ embq)
{
    const int lane = threadIdx.x & 63;
    const int wid  = threadIdx.x >> 6;
    const int c0   = lane * 2;
    float2 wc[16];
    #pragma unroll
    for (int k = 0; k < 16; ++k)
        wc[k] = *reinterpret_cast<const float2*>(&bW[k * 128 + c0]);
    const float2 bbr = *reinterpret_cast<const float2*>(&bb[c0]);

    for (int j = blockIdx.x * 4 + wid; j < NEDGES; j += gridDim.x * 4) {
        const float4* eap = reinterpret_cast<const float4*>(ea_s + (size_t)j * 16);
        const float4 a0 = eap[0], a1 = eap[1], a2 = eap[2], a3 = eap[3];
        float s0 = bbr.x, s1 = bbr.y;
        s0 += a0.x*wc[0].x + a0.y*wc[1].x + a0.z*wc[2].x + a0.w*wc[3].x
            + a1.x*wc[4].x + a1.y*wc[5].x + a1.z*wc[6].x + a1.w*wc[7].x
            + a2.x*wc[8].x + a2.y*wc[9].x + a2.z*wc[10].x + a2.w*wc[11].x
            + a3.x*wc[12].x + a3.y*wc[13].x + a3.z*wc[14].x + a3.w*wc[15].x;
        s1 += a0.x*wc[0].y + a0.y*wc[1].y + a0.z*wc[2].y + a0.w*wc[3].y
            + a1.x*wc[4].y + a1.y*wc[5].y + a1.z*wc[6].y + a1.w*wc[7].y
            + a2.x*wc[8].y + a2.y*wc[9].y + a2.z*wc[10].y + a2.w*wc[11].y
            + a3.x*wc[12].y + a3.y*wc[13].y + a3.z*wc[14].y + a3.w*wc[15].y;
        embq[(size_t)j * 64 + lane] =
            ((uint32_t)f2bf_rne(s1) << 16) | (uint32_t)f2bf_rne(s0);
    }
}

// === weight prep: transposed bf16 for 6 conv + mW1 (16384 ea) + mW2 (8192)
__global__ __launch_bounds__(256) void wtrans_kernel(
    const float* __restrict__ cW1, const float* __restrict__ cW2,
    const float* __restrict__ mW1, const float* __restrict__ mW2,
    short* __restrict__ wbf)
{
    const int gidx = blockIdx.x * 256 + threadIdx.x;   // 122880 total
    if (gidx >= 122880) return;
    if (gidx < 114688) {
        const int m  = gidx >> 14;                      // matrix 0..6
        const int el = gidx & 16383;
        const int n  = el >> 7;
        const int k  = el & 127;
        const float* W = (m < 3) ? (cW1 + m * 16384)
                       : (m < 6) ? (cW2 + (m - 3) * 16384) : mW1;
        wbf[(size_t)m * 16384 + n * 128 + k] = (short)f2bf_rne(W[k * 128 + n]);
    } else {
        const int el = gidx - 114688;                   // mW2: [128][64] -> [64][128]
        const int n  = el >> 7;
        const int k  = el & 127;
        wbf[114688 + n * 128 + k] = (short)f2bf_rne(mW2[k * 64 + n]);
    }
}

// =============== message passing: 1 wave/node, ch-pair/lane ==============
// 2-deep software pipeline (named slots A/B — no runtime-indexed arrays).
__global__ __launch_bounds__(256) void agg2_kernel(
    const float* __restrict__ xsrc, const float* __restrict__ nm,
    const uint32_t* __restrict__ embq, const int* __restrict__ off,
    const int* __restrict__ esrc, const float* __restrict__ epsp, int layer,
    float* __restrict__ hout)
{
    const int lane = threadIdx.x & 63;
    const int wid  = threadIdx.x >> 6;
    const int c0   = lane * 2;
    const float epv = 1.0f + epsp[layer];

    for (int n = blockIdx.x * 4 + wid; n < NNODES; n += gridDim.x * 4) {
        const int j0 = off[n], j1 = off[n + 1];
        float dm[4];
        #pragma unroll
        for (int c = 0; c < 4; ++c) dm[c] = nm[c * NNODES + n];

        float acc[4][2] = {{0.f,0.f},{0.f,0.f},{0.f,0.f},{0.f,0.f}};

        uint32_t eqA = 0, eqB = 0;
        float mvA[4], mvB[4]; float2 xvA[4], xvB[4];

#define PF(EQ, MV, XV, JJ)                                                   \
        {                                                                    \
            const int s_ = esrc[(JJ)];                                       \
            EQ = embq[(size_t)(JJ) * 64 + lane];                             \
            _Pragma("unroll")                                                \
            for (int c = 0; c < 4; ++c) {                                    \
                MV[c] = nm[c * NNODES + s_] * dm[c];                         \
                XV[c] = *reinterpret_cast<const float2*>(                    \
                            &xsrc[((size_t)c * NNODES + s_) * NH + c0]);     \
            }                                                                \
        }
#define CONSUME(EQ, MV, XV)                                                  \
        {                                                                    \
            const float e0_ = __uint_as_float(EQ << 16);                     \
            const float e1_ = __uint_as_float(EQ & 0xffff0000u);             \
            _Pragma("unroll")                                                \
            for (int c = 0; c < 4; ++c) {                                    \
                acc[c][0] += gelu_f(XV[c].x + e0_) * MV[c];                  \
                acc[c][1] += gelu_f(XV[c].y + e1_) * MV[c];                  \
            }                                                                \
        }

        if (j0 < j1)     PF(eqA, mvA, xvA, j0);
        if (j0 + 1 < j1) PF(eqB, mvB, xvB, j0 + 1);
        int j = j0;
        while (j < j1) {
            CONSUME(eqA, mvA, xvA);
            if (j + 2 < j1) PF(eqA, mvA, xvA, j + 2);
            ++j;
            if (j >= j1) break;
            CONSUME(eqB, mvB, xvB);
            if (j + 2 < j1) PF(eqB, mvB, xvB, j + 2);
            ++j;
        }
#undef PF
#undef CONSUME

        #pragma unroll
        for (int c = 0; c < 4; ++c) {
            const float2 xo = *reinterpret_cast<const float2*>(
                                  &xsrc[((size_t)c * NNODES + n) * NH + c0]);
            float2 o;
            o.x = epv * xo.x + acc[c][0];
            o.y = epv * xo.y + acc[c][1];
            *reinterpret_cast<float2*>(&hout[((size_t)c * NNODES + n) * NH + c0]) = o;
        }
    }
}

// ============ fallback agg (round-4 path) ================================
__global__ __launch_bounds__(256) void agg_kernel(
    const float* __restrict__ xcur, const float* __restrict__ nm,
    const float* __restrict__ ea_s, const float* __restrict__ bW,
    const float* __restrict__ bb, const int* __restrict__ off,
    const int* __restrict__ esrc, const float* __restrict__ epsp, int layer,
    float* __restrict__ hout)
{
    const int tid = threadIdx.x;
    const int h   = tid & 127;
    const int sub = tid >> 7;
    float wc[16];
    #pragma unroll
    for (int k = 0; k < 16; ++k) wc[k] = bW[k * 128 + h];
    const float bbr = bb[h];
    const float epv = 1.0f + epsp[layer];

    for (int n = blockIdx.x * 2 + sub; n < NNODES; n += gridDim.x * 2) {
        float acc0 = 0.f, acc1 = 0.f, acc2 = 0.f, acc3 = 0.f;
        const int j0 = off[n], j1 = off[n + 1];
        const float d0 = nm[0*NNODES+n], d1 = nm[1*NNODES+n];
        const float d2 = nm[2*NNODES+n], d3 = nm[3*NNODES+n];
        for (int j = j0; j < j1; ++j) {
            const int src = esrc[j];
            const float4* eap = reinterpret_cast<const float4*>(ea_s + (size_t)j * 16);
            const float4 a0 = eap[0], a1 = eap[1], a2 = eap[2], a3 = eap[3];
            float emb = bbr;
            emb += a0.x*wc[0] + a0.y*wc[1] + a0.z*wc[2] + a0.w*wc[3];
            emb += a1.x*wc[4] + a1.y*wc[5] + a1.z*wc[6] + a1.w*wc[7];
            emb += a2.x*wc[8] + a2.y*wc[9] + a2.z*wc[10] + a2.w*wc[11];
            emb += a3.x*wc[12] + a3.y*wc[13] + a3.z*wc[14] + a3.w*wc[15];
            const float m0 = nm[0*NNODES+src]*d0, m1 = nm[1*NNODES+src]*d1;
            const float m2 = nm[2*NNODES+src]*d2, m3 = nm[3*NNODES+src]*d3;
            acc0 += gelu_f(xcur[((size_t)0*NNODES+src)*NH+h] + emb) * m0;
            acc1 += gelu_f(xcur[((size_t)1*NNODES+src)*NH+h] + emb) * m1;
            acc2 += gelu_f(xcur[((size_t)2*NNODES+src)*NH+h] + emb) * m2;
            acc3 += gelu_f(xcur[((size_t)3*NNODES+src)*NH+h] + emb) * m3;
        }
        hout[((size_t)0*NNODES+n)*NH+h] = epv * xcur[((size_t)0*NNODES+n)*NH+h] + acc0;
        hout[((size_t)1*NNODES+n)*NH+h] = epv * xcur[((size_t)1*NNODES+n)*NH+h] + acc1;
        hout[((size_t)2*NNODES+n)*NH+h] = epv * xcur[((size_t)2*NNODES+n)*NH+h] + acc2;
        hout[((size_t)3*NNODES+n)*NH+h] = epv * xcur[((size_t)3*NNODES+n)*NH+h] + acc3;
    }
}

// -------------------------------------------------------------------------
// MFMA fused conv pair (unchanged from round-10, verified).
// -------------------------------------------------------------------------
__global__ __launch_bounds__(256) void conv_mfma_kernel(
    const float* __restrict__ h, const float* __restrict__ resid,
    const short* __restrict__ W1t, const float* __restrict__ b1,
    const short* __restrict__ W2t, const float* __restrict__ b2,
    float* __restrict__ outp)
{
    __shared__ short sh[FTILE * SSTR];
    __shared__ short st[FTILE * SSTR];
    __shared__ short sw[128 * SSTR];

    const int tid  = threadIdx.x;
    const int lane = tid & 63;
    const int w    = tid >> 6;
    const int l15  = lane & 15;
    const int l4   = lane >> 4;
    const int colb = w * 32;
    const int row0 = blockIdx.x * FTILE;

    for (int i = tid; i < FTILE * 32; i += 256) {
        const int r = i >> 5, q = i & 31;
        const float4 v = reinterpret_cast<const float4*>(h + (size_t)(row0 + r) * NH)[q];
        uint2 pk;
        pk.x = ((uint32_t)f2bf_rne(v.y) << 16) | (uint32_t)f2bf_rne(v.x);
        pk.y = ((uint32_t)f2bf_rne(v.w) << 16) | (uint32_t)f2bf_rne(v.z);
        *reinterpret_cast<uint2*>(&sh[r * SSTR + q * 4]) = pk;
    }
    for (int i = tid; i < 128 * 16; i += 256) {
        const int r = i >> 4, c = i & 15;
        *reinterpret_cast<uint4*>(&sw[r * SSTR + c * 8]) =
            *reinterpret_cast<const uint4*>(&W1t[r * 128 + c * 8]);
    }
    __syncthreads();

    f32x4 a00 = {0,0,0,0}, a01 = {0,0,0,0}, a10 = {0,0,0,0}, a11 = {0,0,0,0};
    #pragma unroll
    for (int s = 0; s < 4; ++s) {
        const int ko = s * 32 + l4 * 8;
        short8v fa0 = *reinterpret_cast<const short8v*>(&sh[(l15)      * SSTR + ko]);
        short8v fa1 = *reinterpret_cast<const short8v*>(&sh[(16 + l15) * SSTR + ko]);
        short8v fb0 = *reinterpret_cast<const short8v*>(&sw[(colb + l15)      * SSTR + ko]);
        short8v fb1 = *reinterpret_cast<const short8v*>(&sw[(colb + 16 + l15) * SSTR + ko]);
        a00 = __builtin_amdgcn_mfma_f32_16x16x32_bf16(fa0, fb0, a00, 0, 0, 0);
        a01 = __builtin_amdgcn_mfma_f32_16x16x32_bf16(fa0, fb1, a01, 0, 0, 0);
        a10 = __builtin_amdgcn_mfma_f32_16x16x32_bf16(fa1, fb0, a10, 0, 0, 0);
        a11 = __builtin_amdgcn_mfma_f32_16x16x32_bf16(fa1, fb1, a11, 0, 0, 0);
    }

    {
        const float bv0 = b1[colb + l15];
        const float bv1 = b1[colb + 16 + l15];
        #pragma unroll
        for (int j = 0; j < 4; ++j) {
            const int r0 = l4 * 4 + j;
            st[r0 * SSTR + colb + l15]             = (short)f2bf_rne(gelu_f(a00[j] + bv0));
            st[r0 * SSTR + colb + 16 + l15]        = (short)f2bf_rne(gelu_f(a01[j] + bv1));
            st[(16 + r0) * SSTR + colb + l15]      = (short)f2bf_rne(gelu_f(a10[j] + bv0));
            st[(16 + r0) * SSTR + colb + 16 + l15] = (short)f2bf_rne(gelu_f(a11[j] + bv1));
        }
    }
    __syncthreads();

    for (int i = tid; i < 128 * 16; i += 256) {
        const int r = i >> 4, c = i & 15;
        *reinterpret_cast<uint4*>(&sw[r * SSTR + c * 8]) =
            *reinterpret_cast<const uint4*>(&W2t[r * 128 + c * 8]);
    }
    __syncthreads();

    a00 = {0,0,0,0}; a01 = {0,0,0,0}; a10 = {0,0,0,0}; a11 = {0,0,0,0};
    #pragma unroll
    for (int s = 0; s < 4; ++s) {
        const int ko = s * 32 + l4 * 8;
        short8v fa0 = *reinterpret_cast<const short8v*>(&st[(l15)      * SSTR + ko]);
        short8v fa1 = *reinterpret_cast<const short8v*>(&st[(16 + l15) * SSTR + ko]);
        short8v fb0 = *reinterpret_cast<const short8v*>(&sw[(colb + l15)      * SSTR + ko]);
        short8v fb1 = *reinterpret_cast<const short8v*>(&sw[(colb + 16 + l15) * SSTR + ko]);
        a00 = __builtin_amdgcn_mfma_f32_16x16x32_bf16(fa0, fb0, a00, 0, 0, 0);
        a01 = __builtin_amdgcn_mfma_f32_16x16x32_bf16(fa0, fb1, a01, 0, 0, 0);
        a10 = __builtin_amdgcn_mfma_f32_16x16x32_bf16(fa1, fb0, a10, 0, 0, 0);
        a11 = __builtin_amdgcn_mfma_f32_16x16x32_bf16(fa1, fb1, a11, 0, 0, 0);
    }

    {
        const float bv0 = b2[colb + l15];
        const float bv1 = b2[colb + 16 + l15];
        #pragma unroll
        for (int j = 0; j < 4; ++j) {
            const int r0 = row0 + l4 * 4 + j;
            const int r1 = r0 + 16;
            const size_t o00 = (size_t)r0 * NH + colb + l15;
            const size_t o01 = (size_t)r0 * NH + colb + 16 + l15;
            const size_t o10 = (size_t)r1 * NH + colb + l15;
            const size_t o11 = (size_t)r1 * NH + colb + 16 + l15;
            outp[o00] = resid[o00] + gelu_f(a00[j] + bv0);
            outp[o01] = resid[o01] + gelu_f(a01[j] + bv1);
            outp[o10] = resid[o10] + gelu_f(a10[j] + bv0);
            outp[o11] = resid[o11] + gelu_f(a11[j] + bv1);
        }
    }
}

// -------------------------------------------------------------------------
// MFMA fused final MLP: t = relu(x@mW1+b1) (bf16 LDS); y = t@mW2+b2;
// oacc[c][:] += y * nm[row]. GEMM2: wave w owns cols w*16..w*16+15.
// -------------------------------------------------------------------------
__global__ __launch_bounds__(256) void mlp_mfma_kernel(
    const float* __restrict__ x,
    const short* __restrict__ W1t, const float* __restrict__ b1,
    const short* __restrict__ W2t,    // [64 n][128 k] bf16
    const float* __restrict__ b2,     // [64]
    const float* __restrict__ nm,     // [40000]
    float* __restrict__ oacc)         // [256]
{
    __shared__ short sx[FTILE * SSTR];
    __shared__ short st[FTILE * SSTR];
    __shared__ short sw[128 * SSTR];
    __shared__ float sacc[256];

    const int tid  = threadIdx.x;
    const int lane = tid & 63;
    const int w    = tid >> 6;
    const int l15  = lane & 15;
    const int l4   = lane >> 4;
    const int colb = w * 32;
    const int row0 = blockIdx.x * FTILE;

    sacc[tid] = 0.0f;

    for (int i = tid; i < FTILE * 32; i += 256) {
        const int r = i >> 5, q = i & 31;
        const float4 v = reinterpret_cast<const float4*>(x + (size_t)(row0 + r) * NH)[q];
        uint2 pk;
        pk.x = ((uint32_t)f2bf_rne(v.y) << 16) | (uint32_t)f2bf_rne(v.x);
        pk.y = ((uint32_t)f2bf_rne(v.w) << 16) | (uint32_t)f2bf_rne(v.z);
        *reinterpret_cast<uint2*>(&sx[r * SSTR + q * 4]) = pk;
    }
    for (int i = tid; i < 128 * 16; i += 256) {
        const int r = i >> 4, c = i & 15;
        *reinterpret_cast<uint4*>(&sw[r * SSTR + c * 8]) =
            *reinterpret_cast<const uint4*>(&W1t[r * 128 + c * 8]);
    }
    __syncthreads();

    // GEMM1: x @ mW1 (each wave: 32 output cols)
    f32x4 a00 = {0,0,0,0}, a01 = {0,0,0,0}, a10 = {0,0,0,0}, a11 = {0,0,0,0};
    #pragma unroll
    for (int s = 0; s < 4; ++s) {
        const int ko = s * 32 + l4 * 8;
        short8v fa0 = *reinterpret_cast<const short8v*>(&sx[(l15)      * SSTR + ko]);
        short8v fa1 = *reinterpret_cast<const short8v*>(&sx[(16 + l15) * SSTR + ko]);
        short8v fb0 = *reinterpret_cast<const short8v*>(&sw[(colb + l15)      * SSTR + ko]);
        short8v fb1 = *reinterpret_cast<const short8v*>(&sw[(colb + 16 + l15) * SSTR + ko]);
        a00 = __builtin_amdgcn_mfma_f32_16x16x32_bf16(fa0, fb0, a00, 0, 0, 0);
        a01 = __builtin_amdgcn_mfma_f32_16x16x32_bf16(fa0, fb1, a01, 0, 0, 0);
        a10 = __builtin_amdgcn_mfma_f32_16x16x32_bf16(fa1, fb0, a10, 0, 0, 0);
        a11 = __builtin_amdgcn_mfma_f32_16x16x32_bf16(fa1, fb1, a11, 0, 0, 0);
    }

    // t = relu(acc + b1) -> st (bf16)
    {
        const float bv0 = b1[colb + l15];
        const float bv1 = b1[colb + 16 + l15];
        #pragma unroll
        for (int j = 0; j < 4; ++j) {
            const int r0 = l4 * 4 + j;
            st[r0 * SSTR + colb + l15]             = (short)f2bf_rne(fmaxf(a00[j] + bv0, 0.f));
            st[r0 * SSTR + colb + 16 + l15]        = (short)f2bf_rne(fmaxf(a01[j] + bv1, 0.f));
            st[(16 + r0) * SSTR + colb + l15]      = (short)f2bf_rne(fmaxf(a10[j] + bv0, 0.f));
            st[(16 + r0) * SSTR + colb + 16 + l15] = (short)f2bf_rne(fmaxf(a11[j] + bv1, 0.f));
        }
    }
    __syncthreads();

    // stage mW2t: 64 rows x 128 k
    for (int i = tid; i < 64 * 16; i += 256) {
        const int r = i >> 4, c = i & 15;
        *reinterpret_cast<uint4*>(&sw[r * SSTR + c * 8]) =
            *reinterpret_cast<const uint4*>(&W2t[r * 128 + c * 8]);
    }
    __syncthreads();

    // GEMM2: t @ mW2 (64-wide; wave w: cols w*16..+15)
    const int colb2 = w * 16;
    f32x4 c0f = {0,0,0,0}, c1f = {0,0,0,0};
    #pragma unroll
    for (int s = 0; s < 4; ++s) {
        const int ko = s * 32 + l4 * 8;
        short8v fa0 = *reinterpret_cast<const short8v*>(&st[(l15)      * SSTR + ko]);
        short8v fa1 = *reinterpret_cast<const short8v*>(&st[(16 + l15) * SSTR + ko]);
        short8v fb  = *reinterpret_cast<const short8v*>(&sw[(colb2 + l15) * SSTR + ko]);
        c0f = __builtin_amdgcn_mfma_f32_16x16x32_bf16(fa0, fb, c0f, 0, 0, 0);
        c1f = __builtin_amdgcn_mfma_f32_16x16x32_bf16(fa1, fb, c1f, 0, 0, 0);
    }

    // masked-sum epilogue (row = row0 + l4*4 + j [+16]; col = colb2 + l15)
    {
        const float bv = b2[colb2 + l15];
        #pragma unroll
        for (int j = 0; j < 4; ++j) {
            const int gr0 = row0 + l4 * 4 + j;
            const int gr1 = gr0 + 16;
            const float w0 = nm[gr0];
            const float w1 = nm[gr1];
            const int cb0 = gr0 / NNODES;
            const int cb1 = gr1 / NNODES;
            atomicAdd(&sacc[cb0 * 64 + colb2 + l15], (c0f[j] + bv) * w0);
            atomicAdd(&sacc[cb1 * 64 + colb2 + l15], (c1f[j] + bv) * w1);
        }
    }

    __syncthreads();
    atomicAdd(&oacc[tid], sacc[tid]);
}

// -------------------------------------------------------------------------
__global__ __launch_bounds__(256) void final_kernel(
    const float* __restrict__ acc, const float* __restrict__ nm,
    float* __restrict__ outp)
{
    const int tid  = threadIdx.x;
    const int c    = tid >> 6;
    const int lane = tid & 63;
    float s = 0.f;
    for (int n = lane; n < NNODES; n += 64) s += nm[c * NNODES + n];
    #pragma unroll
    for (int off = 32; off > 0; off >>= 1) s += __shfl_down(s, off, 64);
    const float denom = __shfl(s, 0, 64);
    outp[tid] = acc[tid] / denom;
}

extern "C" void kernel_launch(void* const* d_in, const int* in_sizes, int n_in,
                              void* d_out, int out_size, void* d_ws, size_t ws_size,
                              hipStream_t stream) {
    const float* x    = (const float*)d_in[0];
    const float* nm   = (const float*)d_in[1];
    const float* ea   = (const float*)d_in[2];
    const float* bW   = (const float*)d_in[3];
    const float* bb   = (const float*)d_in[4];
    const float* cW1  = (const float*)d_in[5];
    const float* cb1  = (const float*)d_in[6];
    const float* cW2  = (const float*)d_in[7];
    const float* cb2  = (const float*)d_in[8];
    const float* eps  = (const float*)d_in[9];
    const float* mW1  = (const float*)d_in[10];
    const float* mb1  = (const float*)d_in[11];
    const float* mW2  = (const float*)d_in[12];
    const float* mb2  = (const float*)d_in[13];
    const int*   ei   = (const int*)d_in[14];

    float* ws = (float*)d_ws;
    const bool big = ws_size >= (size_t)23230260ULL * 4ULL;   // ~93 MB

    if (big) {
        float*    xcur = ws;                         // 5,120,000
        float*    hbuf = ws + 5120000;               // 5,120,000
        float*    oacc = ws + 10240000;              // 256
        float*    ea_s = ws + 10240256;              // 2,560,000 (dead after emb)
        short*    wbf  = (short*)ea_s;               // 122,880 bf16 (aliases ea_s)
        uint32_t* embq = (uint32_t*)(ws + 12800256); // 10,240,000 dwords
        int*      ib   = (int*)(ws + 23040256);
        int* off = ib; int* cur = ib + 10002; int* deg = ib + 20002;
        int* esrc = ib + 30002;

        hipMemsetAsync(deg, 0, 10000 * 4, stream);
        hist_kernel<<<(NEDGES + 255) / 256, 256, 0, stream>>>(ei, deg);
        scan_kernel<<<1, 1024, 0, stream>>>(deg, off, cur);
        scatter_kernel<<<(NEDGES + 255) / 256, 256, 0, stream>>>(ei, ea, cur, esrc, ea_s);
        emb_kernel<<<10000, 256, 0, stream>>>(ea_s, bW, bb, embq);
        wtrans_kernel<<<480, 256, 0, stream>>>(cW1, cW2, mW1, mW2, wbf);  // ea_s dead

        for (int l = 0; l < 3; ++l) {
            const float* xs = (l == 0) ? x : xcur;
            agg2_kernel<<<2500, 256, 0, stream>>>(xs, nm, embq, off, esrc, eps, l, hbuf);
            conv_mfma_kernel<<<FTILES, 256, 0, stream>>>(hbuf, xs,
                wbf + (size_t)l * 16384, cb1 + l * 128,
                wbf + (size_t)(3 + l) * 16384, cb2 + l * 128, xcur);
        }
        hipMemsetAsync(oacc, 0, 256 * 4, stream);
        mlp_mfma_kernel<<<FTILES, 256, 0, stream>>>(xcur, wbf + 98304, mb1,
                                                    wbf + 114688, mb2, nm, oacc);
        final_kernel<<<1, 256, 0, stream>>>(oacc, nm, (float*)d_out);
    } else {
        // fallback (~52.4 MB): round-4 agg + MFMA conv/mlp (wbf after esrc)
        float* xcur = ws;
        float* hbuf = ws + 5120000;
        float* oacc = ws + 10240000;
        float* ea_s = ws + 10240256;
        int*   ib   = (int*)(ws + 12800256);
        int* off = ib; int* cur = ib + 10002; int* deg = ib + 20002;
        int* esrc = ib + 30002;
        short* wbf = (short*)(ib + 190004);

        hipMemsetAsync(deg, 0, 10000 * 4, stream);
        hist_kernel<<<(NEDGES + 255) / 256, 256, 0, stream>>>(ei, deg);
        scan_kernel<<<1, 1024, 0, stream>>>(deg, off, cur);
        scatter_kernel<<<(NEDGES + 255) / 256, 256, 0, stream>>>(ei, ea, cur, esrc, ea_s);
        wtrans_kernel<<<480, 256, 0, stream>>>(cW1, cW2, mW1, mW2, wbf);

        for (int l = 0; l < 3; ++l) {
            const float* xs = (l == 0) ? x : xcur;
            agg_kernel<<<2500, 256, 0, stream>>>(xs, nm, ea_s, bW, bb, off, esrc,
                                                 eps, l, hbuf);
            conv_mfma_kernel<<<FTILES, 256, 0, stream>>>(hbuf, xs,
                wbf + (size_t)l * 16384, cb1 + l * 128,
                wbf + (size_t)(3 + l) * 16384, cb2 + l * 128, xcur);
        }
        hipMemsetAsync(oacc, 0, 256 * 4, stream);
        mlp_mfma_kernel<<<FTILES, 256, 0, stream>>>(xcur, wbf + 98304, mb1,
                                                    wbf + 114688, mb2, nm, oacc);
        final_kernel<<<1, 256, 0, stream>>>(oacc, nm, (float*)d_out);
    }
}

// Round 12
// 441.768 us; speedup vs baseline: 2.6145x; 1.0241x over previous
//
#include <hip/hip_runtime.h>
#include <hip/hip_bf16.h>
#include <cstddef>
#include <cstdint>

#define NNODES 10000
#define NEDGES 160000
#define NH     128
#define NCOMBO 4
#define NMROWS (NCOMBO * NNODES)              // 40000 rows (combo-major)
#define FTILE  32                             // rows per conv/mlp tile
#define SSTR   136                            // bf16 LDS row stride (shorts) = 272B
#define FTILES (NMROWS / FTILE)               // 1250

typedef __attribute__((ext_vector_type(8))) short short8v;   // 8 bf16 (4 VGPR)
typedef __attribute__((ext_vector_type(4))) float f32x4;     // MFMA accumulator

// Branchless erf-gelu via Abramowitz-Stegun 7.1.26 (|erf err| <= 1.5e-7).
__device__ __forceinline__ float gelu_f(float v) {
    const float u  = v * 0.70710678118654752f;
    float au = __builtin_fabsf(u);
    au = fminf(au, 3.9192f);
    const float t  = __builtin_amdgcn_rcpf(__builtin_fmaf(0.3275911f, au, 1.0f));
    const float e  = __builtin_amdgcn_exp2f(au * au * -1.4426950408889634f);
    float p = __builtin_fmaf(1.061405429f, t, -1.453152027f);
    p = __builtin_fmaf(p, t, 1.421413741f);
    p = __builtin_fmaf(p, t, -0.284496736f);
    p = __builtin_fmaf(p, t, 0.254829592f);
    const float erf_abs = 1.0f - p * t * e;
    const float erf_s   = __builtin_copysignf(erf_abs, v);
    return 0.5f * v * (1.0f + erf_s);
}

__device__ __forceinline__ uint16_t f2bf_rne(float f) {
    const uint32_t x = __float_as_uint(f);
    return (uint16_t)((x + 0x7fffu + ((x >> 16) & 1u)) >> 16);
}
__device__ __forceinline__ uint32_t packbf2(float lo, float hi) {
    return ((uint32_t)f2bf_rne(hi) << 16) | (uint32_t)f2bf_rne(lo);
}
__device__ __forceinline__ float bflo(uint32_t u) { return __uint_as_float(u << 16); }
__device__ __forceinline__ float bfhi(uint32_t u) { return __uint_as_float(u & 0xffff0000u); }

// ========================= CSR build (by dst) ============================
__global__ __launch_bounds__(256) void hist_kernel(const int* __restrict__ ei,
                                                   int* __restrict__ deg) {
    const int e = blockIdx.x * 256 + threadIdx.x;
    if (e < NEDGES) atomicAdd(&deg[ei[NEDGES + e]], 1);
}

__global__ __launch_bounds__(1024) void scan_kernel(const int* __restrict__ deg,
                                                    int* __restrict__ off,
                                                    int* __restrict__ cursor) {
    __shared__ int ssum[1024];
    const int tid  = threadIdx.x;
    const int base = tid * 10;
    int loc[10];
    int s = 0;
    #pragma unroll
    for (int i = 0; i < 10; ++i) {
        const int idx = base + i;
        loc[i] = s;
        s += (idx < NNODES) ? deg[idx] : 0;
    }
    ssum[tid] = s;
    for (int d = 1; d < 1024; d <<= 1) {
        __syncthreads();
        const int t = (tid >= d) ? ssum[tid - d] : 0;
        __syncthreads();
        ssum[tid] += t;
    }
    __syncthreads();
    const int pref = ssum[tid] - s;
    #pragma unroll
    for (int i = 0; i < 10; ++i) {
        const int idx = base + i;
        if (idx < NNODES) { off[idx] = pref + loc[i]; cursor[idx] = pref + loc[i]; }
    }
    if (tid == 0) off[NNODES] = NEDGES;
}

__global__ __launch_bounds__(256) void scatter_kernel(const int* __restrict__ ei,
                                                      const float* __restrict__ ea,
                                                      int* __restrict__ cursor,
                                                      int* __restrict__ esrc,
                                                      float* __restrict__ ea_s) {
    const int e = blockIdx.x * 256 + threadIdx.x;
    if (e < NEDGES) {
        const int src = ei[e];
        const int dst = ei[NEDGES + e];
        const int pos = atomicAdd(&cursor[dst], 1);
        esrc[pos] = src;
        const float4* s = reinterpret_cast<const float4*>(ea + (size_t)e * 16);
        float4*       d = reinterpret_cast<float4*>(ea_s + (size_t)pos * 16);
        d[0] = s[0]; d[1] = s[1]; d[2] = s[2]; d[3] = s[3];
    }
}

// ============= bond embedding, precomputed once, bf16, CSR order =========
__global__ __launch_bounds__(256) void emb_kernel(
    const float* __restrict__ ea_s, const float* __restrict__ bW,
    const float* __restrict__ bb, uint32_t* __restrict__ embq)
{
    const int lane = threadIdx.x & 63;
    const int wid  = threadIdx.x >> 6;
    const int c0   = lane * 2;
    float2 wc[16];
    #pragma unroll
    for (int k = 0; k < 16; ++k)
        wc[k] = *reinterpret_cast<const float2*>(&bW[k * 128 + c0]);
    const float2 bbr = *reinterpret_cast<const float2*>(&bb[c0]);

    for (int j = blockIdx.x * 4 + wid; j < NEDGES; j += gridDim.x * 4) {
        const float4* eap = reinterpret_cast<const float4*>(ea_s + (size_t)j * 16);
        const float4 a0 = eap[0], a1 = eap[1], a2 = eap[2], a3 = eap[3];
        float s0 = bbr.x, s1 = bbr.y;
        s0 += a0.x*wc[0].x + a0.y*wc[1].x + a0.z*wc[2].x + a0.w*wc[3].x
            + a1.x*wc[4].x + a1.y*wc[5].x + a1.z*wc[6].x + a1.w*wc[7].x
            + a2.x*wc[8].x + a2.y*wc[9].x + a2.z*wc[10].x + a2.w*wc[11].x
            + a3.x*wc[12].x + a3.y*wc[13].x + a3.z*wc[14].x + a3.w*wc[15].x;
        s1 += a0.x*wc[0].y + a0.y*wc[1].y + a0.z*wc[2].y + a0.w*wc[3].y
            + a1.x*wc[4].y + a1.y*wc[5].y + a1.z*wc[6].y + a1.w*wc[7].y
            + a2.x*wc[8].y + a2.y*wc[9].y + a2.z*wc[10].y + a2.w*wc[11].y
            + a3.x*wc[12].y + a3.y*wc[13].y + a3.z*wc[14].y + a3.w*wc[15].y;
        embq[(size_t)j * 64 + lane] = packbf2(s0, s1);
    }
}

// === weight prep: transposed bf16 for 6 conv + mW1 (16384 ea) + mW2 (8192)
__global__ __launch_bounds__(256) void wtrans_kernel(
    const float* __restrict__ cW1, const float* __restrict__ cW2,
    const float* __restrict__ mW1, const float* __restrict__ mW2,
    short* __restrict__ wbf)
{
    const int gidx = blockIdx.x * 256 + threadIdx.x;   // 122880 total
    if (gidx >= 122880) return;
    if (gidx < 114688) {
        const int m  = gidx >> 14;                      // matrix 0..6
        const int el = gidx & 16383;
        const int n  = el >> 7;
        const int k  = el & 127;
        const float* W = (m < 3) ? (cW1 + m * 16384)
                       : (m < 6) ? (cW2 + (m - 3) * 16384) : mW1;
        wbf[(size_t)m * 16384 + n * 128 + k] = (short)f2bf_rne(W[k * 128 + n]);
    } else {
        const int el = gidx - 114688;                   // mW2: [128][64] -> [64][128]
        const int n  = el >> 7;
        const int k  = el & 127;
        wbf[114688 + n * 128 + k] = (short)f2bf_rne(mW2[k * 64 + n]);
    }
}

// === x -> packed bf16 mirror (layer-0 input) =============================
__global__ __launch_bounds__(256) void xcast_kernel(const float* __restrict__ x,
                                                    uint32_t* __restrict__ xbf) {
    const int i = blockIdx.x * 256 + threadIdx.x;      // over 2,560,000 uints
    if (i < NMROWS * 64) {
        const float2 v = *reinterpret_cast<const float2*>(&x[(size_t)i * 2]);
        xbf[i] = packbf2(v.x, v.y);
    }
}

// =============== message passing: 1 wave/node, ch-pair/lane, bf16 x ======
// hbf[c,n,:] = bf16( (1+eps)*x[c,n,:] + sum_j gelu(x[c,src]+emb_j)*m )
__global__ __launch_bounds__(256) void agg2_kernel(
    const uint32_t* __restrict__ xbf, // [4][N][64] packed bf16 pairs
    const float* __restrict__ nm,     // [4][N]
    const uint32_t* __restrict__ embq,// [E][64] packed bf16 pairs
    const int*   __restrict__ off,    // [N+1]
    const int*   __restrict__ esrc,   // [E] CSR src
    const float* __restrict__ epsp, int layer,
    uint32_t* __restrict__ hbf)       // [4][N][64] packed bf16 pairs
{
    const int lane = threadIdx.x & 63;
    const int wid  = threadIdx.x >> 6;
    const float epv = 1.0f + epsp[layer];

    for (int n = blockIdx.x * 4 + wid; n < NNODES; n += gridDim.x * 4) {
        const int j0 = off[n], j1 = off[n + 1];
        float dm[4];
        #pragma unroll
        for (int c = 0; c < 4; ++c) dm[c] = nm[c * NNODES + n];

        float acc[4][2] = {{0.f,0.f},{0.f,0.f},{0.f,0.f},{0.f,0.f}};

        // 1-deep software pipeline (round-8/10 proven structure)
        uint32_t eq_c = 0; float mv_c[4]; uint32_t xu_c[4];
        if (j0 < j1) {
            const int s = esrc[j0];
            eq_c = embq[(size_t)j0 * 64 + lane];
            #pragma unroll
            for (int c = 0; c < 4; ++c) {
                mv_c[c] = nm[c * NNODES + s] * dm[c];
                xu_c[c] = xbf[((size_t)c * NNODES + s) * 64 + lane];
            }
        }
        for (int j = j0; j < j1; ++j) {
            const uint32_t eq = eq_c;
            float mv[4]; uint32_t xu[4];
            #pragma unroll
            for (int c = 0; c < 4; ++c) { mv[c] = mv_c[c]; xu[c] = xu_c[c]; }
            if (j + 1 < j1) {
                const int s = esrc[j + 1];
                eq_c = embq[(size_t)(j + 1) * 64 + lane];
                #pragma unroll
                for (int c = 0; c < 4; ++c) {
                    mv_c[c] = nm[c * NNODES + s] * dm[c];
                    xu_c[c] = xbf[((size_t)c * NNODES + s) * 64 + lane];
                }
            }
            const float e0 = bflo(eq);
            const float e1 = bfhi(eq);
            #pragma unroll
            for (int c = 0; c < 4; ++c) {
                acc[c][0] += gelu_f(bflo(xu[c]) + e0) * mv[c];
                acc[c][1] += gelu_f(bfhi(xu[c]) + e1) * mv[c];
            }
        }
        #pragma unroll
        for (int c = 0; c < 4; ++c) {
            const uint32_t u = xbf[((size_t)c * NNODES + n) * 64 + lane];
            const float o0 = epv * bflo(u) + acc[c][0];
            const float o1 = epv * bfhi(u) + acc[c][1];
            hbf[((size_t)c * NNODES + n) * 64 + lane] = packbf2(o0, o1);
        }
    }
}

// ============ fallback agg (fp32 gather, bf16 h out) =====================
__global__ __launch_bounds__(256) void agg_kernel(
    const float* __restrict__ xcur, const float* __restrict__ nm,
    const float* __restrict__ ea_s, const float* __restrict__ bW,
    const float* __restrict__ bb, const int* __restrict__ off,
    const int* __restrict__ esrc, const float* __restrict__ epsp, int layer,
    short* __restrict__ hbf_s)
{
    const int tid = threadIdx.x;
    const int h   = tid & 127;
    const int sub = tid >> 7;
    float wc[16];
    #pragma unroll
    for (int k = 0; k < 16; ++k) wc[k] = bW[k * 128 + h];
    const float bbr = bb[h];
    const float epv = 1.0f + epsp[layer];

    for (int n = blockIdx.x * 2 + sub; n < NNODES; n += gridDim.x * 2) {
        float acc0 = 0.f, acc1 = 0.f, acc2 = 0.f, acc3 = 0.f;
        const int j0 = off[n], j1 = off[n + 1];
        const float d0 = nm[0*NNODES+n], d1 = nm[1*NNODES+n];
        const float d2 = nm[2*NNODES+n], d3 = nm[3*NNODES+n];
        for (int j = j0; j < j1; ++j) {
            const int src = esrc[j];
            const float4* eap = reinterpret_cast<const float4*>(ea_s + (size_t)j * 16);
            const float4 a0 = eap[0], a1 = eap[1], a2 = eap[2], a3 = eap[3];
            float emb = bbr;
            emb += a0.x*wc[0] + a0.y*wc[1] + a0.z*wc[2] + a0.w*wc[3];
            emb += a1.x*wc[4] + a1.y*wc[5] + a1.z*wc[6] + a1.w*wc[7];
            emb += a2.x*wc[8] + a2.y*wc[9] + a2.z*wc[10] + a2.w*wc[11];
            emb += a3.x*wc[12] + a3.y*wc[13] + a3.z*wc[14] + a3.w*wc[15];
            const float m0 = nm[0*NNODES+src]*d0, m1 = nm[1*NNODES+src]*d1;
            const float m2 = nm[2*NNODES+src]*d2, m3 = nm[3*NNODES+src]*d3;
            acc0 += gelu_f(xcur[((size_t)0*NNODES+src)*NH+h] + emb) * m0;
            acc1 += gelu_f(xcur[((size_t)1*NNODES+src)*NH+h] + emb) * m1;
            acc2 += gelu_f(xcur[((size_t)2*NNODES+src)*NH+h] + emb) * m2;
            acc3 += gelu_f(xcur[((size_t)3*NNODES+src)*NH+h] + emb) * m3;
        }
        hbf_s[((size_t)0*NNODES+n)*NH+h] = (short)f2bf_rne(epv * xcur[((size_t)0*NNODES+n)*NH+h] + acc0);
        hbf_s[((size_t)1*NNODES+n)*NH+h] = (short)f2bf_rne(epv * xcur[((size_t)1*NNODES+n)*NH+h] + acc1);
        hbf_s[((size_t)2*NNODES+n)*NH+h] = (short)f2bf_rne(epv * xcur[((size_t)2*NNODES+n)*NH+h] + acc2);
        hbf_s[((size_t)3*NNODES+n)*NH+h] = (short)f2bf_rne(epv * xcur[((size_t)3*NNODES+n)*NH+h] + acc3);
    }
}

// -------------------------------------------------------------------------
// MFMA fused conv pair; h arrives pre-packed bf16; emits fp32 xcur + bf16 xbf.
// Fragments (16x16x32 bf16): A/B lane l: 8 contig k at (l>>4)*8; row/col l&15.
// C/D: col = l&15, row = (l>>4)*4 + reg  [m89-verified].
// -------------------------------------------------------------------------
__global__ __launch_bounds__(256) void conv_mfma_kernel(
    const uint32_t* __restrict__ hb,  // [40000][64] packed bf16
    const float* __restrict__ resid,  // [40000][128] fp32
    const short* __restrict__ W1t, const float* __restrict__ b1,
    const short* __restrict__ W2t, const float* __restrict__ b2,
    float* __restrict__ outp,         // [40000][128] fp32
    short* __restrict__ xb_s)         // [40000][128] bf16 mirror
{
    __shared__ short sh[FTILE * SSTR];
    __shared__ short st[FTILE * SSTR];
    __shared__ short sw[128 * SSTR];

    const int tid  = threadIdx.x;
    const int lane = tid & 63;
    const int w    = tid >> 6;
    const int l15  = lane & 15;
    const int l4   = lane >> 4;
    const int colb = w * 32;
    const int row0 = blockIdx.x * FTILE;

    // stage h tile (already bf16: straight 16B copies)
    for (int i = tid; i < FTILE * 16; i += 256) {
        const int r = i >> 4, c = i & 15;
        *reinterpret_cast<uint4*>(&sh[r * SSTR + c * 8]) =
            *reinterpret_cast<const uint4*>(&hb[(size_t)(row0 + r) * 64 + c * 4]);
    }
    for (int i = tid; i < 128 * 16; i += 256) {
        const int r = i >> 4, c = i & 15;
        *reinterpret_cast<uint4*>(&sw[r * SSTR + c * 8]) =
            *reinterpret_cast<const uint4*>(&W1t[r * 128 + c * 8]);
    }
    __syncthreads();

    f32x4 a00 = {0,0,0,0}, a01 = {0,0,0,0}, a10 = {0,0,0,0}, a11 = {0,0,0,0};
    #pragma unroll
    for (int s = 0; s < 4; ++s) {
        const int ko = s * 32 + l4 * 8;
        short8v fa0 = *reinterpret_cast<const short8v*>(&sh[(l15)      * SSTR + ko]);
        short8v fa1 = *reinterpret_cast<const short8v*>(&sh[(16 + l15) * SSTR + ko]);
        short8v fb0 = *reinterpret_cast<const short8v*>(&sw[(colb + l15)      * SSTR + ko]);
        short8v fb1 = *reinterpret_cast<const short8v*>(&sw[(colb + 16 + l15) * SSTR + ko]);
        a00 = __builtin_amdgcn_mfma_f32_16x16x32_bf16(fa0, fb0, a00, 0, 0, 0);
        a01 = __builtin_amdgcn_mfma_f32_16x16x32_bf16(fa0, fb1, a01, 0, 0, 0);
        a10 = __builtin_amdgcn_mfma_f32_16x16x32_bf16(fa1, fb0, a10, 0, 0, 0);
        a11 = __builtin_amdgcn_mfma_f32_16x16x32_bf16(fa1, fb1, a11, 0, 0, 0);
    }

    {
        const float bv0 = b1[colb + l15];
        const float bv1 = b1[colb + 16 + l15];
        #pragma unroll
        for (int j = 0; j < 4; ++j) {
            const int r0 = l4 * 4 + j;
            st[r0 * SSTR + colb + l15]             = (short)f2bf_rne(gelu_f(a00[j] + bv0));
            st[r0 * SSTR + colb + 16 + l15]        = (short)f2bf_rne(gelu_f(a01[j] + bv1));
            st[(16 + r0) * SSTR + colb + l15]      = (short)f2bf_rne(gelu_f(a10[j] + bv0));
            st[(16 + r0) * SSTR + colb + 16 + l15] = (short)f2bf_rne(gelu_f(a11[j] + bv1));
        }
    }
    __syncthreads();

    for (int i = tid; i < 128 * 16; i += 256) {
        const int r = i >> 4, c = i & 15;
        *reinterpret_cast<uint4*>(&sw[r * SSTR + c * 8]) =
            *reinterpret_cast<const uint4*>(&W2t[r * 128 + c * 8]);
    }
    __syncthreads();

    a00 = {0,0,0,0}; a01 = {0,0,0,0}; a10 = {0,0,0,0}; a11 = {0,0,0,0};
    #pragma unroll
    for (int s = 0; s < 4; ++s) {
        const int ko = s * 32 + l4 * 8;
        short8v fa0 = *reinterpret_cast<const short8v*>(&st[(l15)      * SSTR + ko]);
        short8v fa1 = *reinterpret_cast<const short8v*>(&st[(16 + l15) * SSTR + ko]);
        short8v fb0 = *reinterpret_cast<const short8v*>(&sw[(colb + l15)      * SSTR + ko]);
        short8v fb1 = *reinterpret_cast<const short8v*>(&sw[(colb + 16 + l15) * SSTR + ko]);
        a00 = __builtin_amdgcn_mfma_f32_16x16x32_bf16(fa0, fb0, a00, 0, 0, 0);
        a01 = __builtin_amdgcn_mfma_f32_16x16x32_bf16(fa0, fb1, a01, 0, 0, 0);
        a10 = __builtin_amdgcn_mfma_f32_16x16x32_bf16(fa1, fb0, a10, 0, 0, 0);
        a11 = __builtin_amdgcn_mfma_f32_16x16x32_bf16(fa1, fb1, a11, 0, 0, 0);
    }

    {
        const float bv0 = b2[colb + l15];
        const float bv1 = b2[colb + 16 + l15];
        #pragma unroll
        for (int j = 0; j < 4; ++j) {
            const int r0 = row0 + l4 * 4 + j;
            const int r1 = r0 + 16;
            const size_t o00 = (size_t)r0 * NH + colb + l15;
            const size_t o01 = (size_t)r0 * NH + colb + 16 + l15;
            const size_t o10 = (size_t)r1 * NH + colb + l15;
            const size_t o11 = (size_t)r1 * NH + colb + 16 + l15;
            const float v00 = resid[o00] + gelu_f(a00[j] + bv0);
            const float v01 = resid[o01] + gelu_f(a01[j] + bv1);
            const float v10 = resid[o10] + gelu_f(a10[j] + bv0);
            const float v11 = resid[o11] + gelu_f(a11[j] + bv1);
            outp[o00] = v00; xb_s[o00] = (short)f2bf_rne(v00);
            outp[o01] = v01; xb_s[o01] = (short)f2bf_rne(v01);
            outp[o10] = v10; xb_s[o10] = (short)f2bf_rne(v10);
            outp[o11] = v11; xb_s[o11] = (short)f2bf_rne(v11);
        }
    }
}

// -------------------------------------------------------------------------
// MFMA fused final MLP: input from xbf (packed bf16).
// -------------------------------------------------------------------------
__global__ __launch_bounds__(256) void mlp_mfma_kernel(
    const uint32_t* __restrict__ xb,  // [40000][64] packed bf16
    const short* __restrict__ W1t, const float* __restrict__ b1,
    const short* __restrict__ W2t,    // [64 n][128 k] bf16
    const float* __restrict__ b2,     // [64]
    const float* __restrict__ nm,     // [40000]
    float* __restrict__ oacc)         // [256]
{
    __shared__ short sx[FTILE * SSTR];
    __shared__ short st[FTILE * SSTR];
    __shared__ short sw[128 * SSTR];
    __shared__ float sacc[256];

    const int tid  = threadIdx.x;
    const int lane = tid & 63;
    const int w    = tid >> 6;
    const int l15  = lane & 15;
    const int l4   = lane >> 4;
    const int colb = w * 32;
    const int row0 = blockIdx.x * FTILE;

    sacc[tid] = 0.0f;

    for (int i = tid; i < FTILE * 16; i += 256) {
        const int r = i >> 4, c = i & 15;
        *reinterpret_cast<uint4*>(&sx[r * SSTR + c * 8]) =
            *reinterpret_cast<const uint4*>(&xb[(size_t)(row0 + r) * 64 + c * 4]);
    }
    for (int i = tid; i < 128 * 16; i += 256) {
        const int r = i >> 4, c = i & 15;
        *reinterpret_cast<uint4*>(&sw[r * SSTR + c * 8]) =
            *reinterpret_cast<const uint4*>(&W1t[r * 128 + c * 8]);
    }
    __syncthreads();

    f32x4 a00 = {0,0,0,0}, a01 = {0,0,0,0}, a10 = {0,0,0,0}, a11 = {0,0,0,0};
    #pragma unroll
    for (int s = 0; s < 4; ++s) {
        const int ko = s * 32 + l4 * 8;
        short8v fa0 = *reinterpret_cast<const short8v*>(&sx[(l15)      * SSTR + ko]);
        short8v fa1 = *reinterpret_cast<const short8v*>(&sx[(16 + l15) * SSTR + ko]);
        short8v fb0 = *reinterpret_cast<const short8v*>(&sw[(colb + l15)      * SSTR + ko]);
        short8v fb1 = *reinterpret_cast<const short8v*>(&sw[(colb + 16 + l15) * SSTR + ko]);
        a00 = __builtin_amdgcn_mfma_f32_16x16x32_bf16(fa0, fb0, a00, 0, 0, 0);
        a01 = __builtin_amdgcn_mfma_f32_16x16x32_bf16(fa0, fb1, a01, 0, 0, 0);
        a10 = __builtin_amdgcn_mfma_f32_16x16x32_bf16(fa1, fb0, a10, 0, 0, 0);
        a11 = __builtin_amdgcn_mfma_f32_16x16x32_bf16(fa1, fb1, a11, 0, 0, 0);
    }

    {
        const float bv0 = b1[colb + l15];
        const float bv1 = b1[colb + 16 + l15];
        #pragma unroll
        for (int j = 0; j < 4; ++j) {
            const int r0 = l4 * 4 + j;
            st[r0 * SSTR + colb + l15]             = (short)f2bf_rne(fmaxf(a00[j] + bv0, 0.f));
            st[r0 * SSTR + colb + 16 + l15]        = (short)f2bf_rne(fmaxf(a01[j] + bv1, 0.f));
            st[(16 + r0) * SSTR + colb + l15]      = (short)f2bf_rne(fmaxf(a10[j] + bv0, 0.f));
            st[(16 + r0) * SSTR + colb + 16 + l15] = (short)f2bf_rne(fmaxf(a11[j] + bv1, 0.f));
        }
    }
    __syncthreads();

    for (int i = tid; i < 64 * 16; i += 256) {
        const int r = i >> 4, c = i & 15;
        *reinterpret_cast<uint4*>(&sw[r * SSTR + c * 8]) =
            *reinterpret_cast<const uint4*>(&W2t[r * 128 + c * 8]);
    }
    __syncthreads();

    const int colb2 = w * 16;
    f32x4 c0f = {0,0,0,0}, c1f = {0,0,0,0};
    #pragma unroll
    for (int s = 0; s < 4; ++s) {
        const int ko = s * 32 + l4 * 8;
        short8v fa0 = *reinterpret_cast<const short8v*>(&st[(l15)      * SSTR + ko]);
        short8v fa1 = *reinterpret_cast<const short8v*>(&st[(16 + l15) * SSTR + ko]);
        short8v fb  = *reinterpret_cast<const short8v*>(&sw[(colb2 + l15) * SSTR + ko]);
        c0f = __builtin_amdgcn_mfma_f32_16x16x32_bf16(fa0, fb, c0f, 0, 0, 0);
        c1f = __builtin_amdgcn_mfma_f32_16x16x32_bf16(fa1, fb, c1f, 0, 0, 0);
    }

    {
        const float bv = b2[colb2 + l15];
        #pragma unroll
        for (int j = 0; j < 4; ++j) {
            const int gr0 = row0 + l4 * 4 + j;
            const int gr1 = gr0 + 16;
            const float w0 = nm[gr0];
            const float w1 = nm[gr1];
            const int cb0 = gr0 / NNODES;
            const int cb1 = gr1 / NNODES;
            atomicAdd(&sacc[cb0 * 64 + colb2 + l15], (c0f[j] + bv) * w0);
            atomicAdd(&sacc[cb1 * 64 + colb2 + l15], (c1f[j] + bv) * w1);
        }
    }

    __syncthreads();
    atomicAdd(&oacc[tid], sacc[tid]);
}

// -------------------------------------------------------------------------
__global__ __launch_bounds__(256) void final_kernel(
    const float* __restrict__ acc, const float* __restrict__ nm,
    float* __restrict__ outp)
{
    const int tid  = threadIdx.x;
    const int c    = tid >> 6;
    const int lane = tid & 63;
    float s = 0.f;
    for (int n = lane; n < NNODES; n += 64) s += nm[c * NNODES + n];
    #pragma unroll
    for (int off = 32; off > 0; off >>= 1) s += __shfl_down(s, off, 64);
    const float denom = __shfl(s, 0, 64);
    outp[tid] = acc[tid] / denom;
}

extern "C" void kernel_launch(void* const* d_in, const int* in_sizes, int n_in,
                              void* d_out, int out_size, void* d_ws, size_t ws_size,
                              hipStream_t stream) {
    const float* x    = (const float*)d_in[0];
    const float* nm   = (const float*)d_in[1];
    const float* ea   = (const float*)d_in[2];
    const float* bW   = (const float*)d_in[3];
    const float* bb   = (const float*)d_in[4];
    const float* cW1  = (const float*)d_in[5];
    const float* cb1  = (const float*)d_in[6];
    const float* cW2  = (const float*)d_in[7];
    const float* cb2  = (const float*)d_in[8];
    const float* eps  = (const float*)d_in[9];
    const float* mW1  = (const float*)d_in[10];
    const float* mb1  = (const float*)d_in[11];
    const float* mW2  = (const float*)d_in[12];
    const float* mb2  = (const float*)d_in[13];
    const int*   ei   = (const int*)d_in[14];

    float* ws = (float*)d_ws;
    const bool big = ws_size >= (size_t)23230600ULL * 4ULL;   // ~93 MB

    if (big) {
        float*    xcur = ws;                           // 5,120,000
        float*    oacc = ws + 5120000;                 // 256
        uint32_t* hbf  = (uint32_t*)(ws + 5120512);    // 2,560,000 uints
        uint32_t* xbf  = (uint32_t*)(ws + 7680512);    // 2,560,000 uints
        float*    ea_s = ws + 10240512;                // 2,560,000 (dead after emb)
        short*    wbf  = (short*)ea_s;                 // 122,880 bf16 (aliases ea_s)
        uint32_t* embq = (uint32_t*)(ws + 12800512);   // 10,240,000 uints
        int*      ib   = (int*)(ws + 23040512);
        int* off = ib; int* cur = ib + 10002; int* deg = ib + 20002;
        int* esrc = ib + 30002;

        hipMemsetAsync(deg, 0, 10000 * 4, stream);
        hist_kernel<<<(NEDGES + 255) / 256, 256, 0, stream>>>(ei, deg);
        scan_kernel<<<1, 1024, 0, stream>>>(deg, off, cur);
        scatter_kernel<<<(NEDGES + 255) / 256, 256, 0, stream>>>(ei, ea, cur, esrc, ea_s);
        emb_kernel<<<10000, 256, 0, stream>>>(ea_s, bW, bb, embq);
        wtrans_kernel<<<480, 256, 0, stream>>>(cW1, cW2, mW1, mW2, wbf);  // ea_s dead
        xcast_kernel<<<10000, 256, 0, stream>>>(x, xbf);

        for (int l = 0; l < 3; ++l) {
            const float* resid = (l == 0) ? x : xcur;
            agg2_kernel<<<2500, 256, 0, stream>>>(xbf, nm, embq, off, esrc, eps, l, hbf);
            conv_mfma_kernel<<<FTILES, 256, 0, stream>>>(hbf, resid,
                wbf + (size_t)l * 16384, cb1 + l * 128,
                wbf + (size_t)(3 + l) * 16384, cb2 + l * 128,
                xcur, (short*)xbf);
        }
        hipMemsetAsync(oacc, 0, 256 * 4, stream);
        mlp_mfma_kernel<<<FTILES, 256, 0, stream>>>(xbf, wbf + 98304, mb1,
                                                    wbf + 114688, mb2, nm, oacc);
        final_kernel<<<1, 256, 0, stream>>>(oacc, nm, (float*)d_out);
    } else {
        // fallback (~52.3 MB): fp32-gather agg + MFMA conv/mlp
        float*    xcur = ws;                           // 5,120,000
        float*    oacc = ws + 5120000;                 // 256
        uint32_t* hbf  = (uint32_t*)(ws + 5120512);    // 2,560,000 uints
        uint32_t* xbf  = (uint32_t*)(ws + 7680512);    // 2,560,000 uints
        float*    ea_s = ws + 10240512;                // 2,560,000
        int*      ib   = (int*)(ws + 12800512);
        int* off = ib; int* cur = ib + 10002; int* deg = ib + 20002;
        int* esrc = ib + 30002;
        short* wbf = (short*)(ib + 190004);            // 122,880 shorts

        hipMemcpyAsync(xcur, x, (size_t)5120000 * 4, hipMemcpyDeviceToDevice, stream);
        hipMemsetAsync(deg, 0, 10000 * 4, stream);
        hist_kernel<<<(NEDGES + 255) / 256, 256, 0, stream>>>(ei, deg);
        scan_kernel<<<1, 1024, 0, stream>>>(deg, off, cur);
        scatter_kernel<<<(NEDGES + 255) / 256, 256, 0, stream>>>(ei, ea, cur, esrc, ea_s);
        wtrans_kernel<<<480, 256, 0, stream>>>(cW1, cW2, mW1, mW2, wbf);

        for (int l = 0; l < 3; ++l) {
            agg_kernel<<<2500, 256, 0, stream>>>(xcur, nm, ea_s, bW, bb, off, esrc,
                                                 eps, l, (short*)hbf);
            conv_mfma_kernel<<<FTILES, 256, 0, stream>>>(hbf, xcur,
                wbf + (size_t)l * 16384, cb1 + l * 128,
                wbf + (size_t)(3 + l) * 16384, cb2 + l * 128,
                xcur, (short*)xbf);
        }
        hipMemsetAsync(oacc, 0, 256 * 4, stream);
        mlp_mfma_kernel<<<FTILES, 256, 0, stream>>>(xbf, wbf + 98304, mb1,
                                                    wbf + 114688, mb2, nm, oacc);
        final_kernel<<<1, 256, 0, stream>>>(oacc, nm, (float*)d_out);
    }
}